// Round 7
// baseline (506.035 us; speedup 1.0000x reference)
//
#include <hip/hip_runtime.h>
#include <hip/hip_bf16.h>
#include <math.h>

#define N_GRAPHS 64
#define N_CLASSES 10
#define FIXSCALE 1048576.0f  // 2^20 fixed-point scale for packed degree sum

// ---------------- init: zero packed hist + pooling buffers ----------------
__global__ void init_k(unsigned long long* __restrict__ packed,
                       float* __restrict__ sums, float* __restrict__ cntG, int n) {
    int i = blockIdx.x * 256 + threadIdx.x;
    if (i < n) packed[i] = 0ull;
    if (i < N_GRAPHS * 64) sums[i] = 0.0f;
    if (i < N_GRAPHS) cntG[i] = 0.0f;
}

// ---------------- one 64-bit atomic per edge: count<<40 | fix(sigmoid(P)) ----------------
__global__ void hist_k(const float* __restrict__ P, const int* __restrict__ col,
                       unsigned long long* __restrict__ packed, int E) {
    int e = blockIdx.x * 256 + threadIdx.x;
    if (e < E) {
        float s = 1.0f / (1.0f + expf(-P[e]));
        unsigned long long v =
            (1ull << 40) | (unsigned long long)(s * FIXSCALE + 0.5f);
        atomicAdd(&packed[col[e]], v);
    }
}

// ---------------- dis = (1 + sum_w)^-0.5 from packed ----------------
__global__ void dis_k(const unsigned long long* __restrict__ packed,
                      float* __restrict__ dis, int n) {
    int i = blockIdx.x * 256 + threadIdx.x;
    if (i < n) {
        float deg = 1.0f + (float)(packed[i] & ((1ull << 40) - 1)) * (1.0f / FIXSCALE);
        dis[i] = 1.0f / sqrtf(deg);
    }
}

// ---------------- scan stage 1: per-block inclusive scan of counts ----------------
__global__ __launch_bounds__(256) void blockscan_k(const unsigned long long* __restrict__ packed,
                                                   int* __restrict__ scanTmp,
                                                   int* __restrict__ partials, int n) {
    __shared__ int sd[256];
    int t = threadIdx.x;
    int i = blockIdx.x * 256 + t;
    int v = (i < n) ? (int)(packed[i] >> 40) : 0;
    sd[t] = v;
    __syncthreads();
    for (int o = 1; o < 256; o <<= 1) {
        int x = (t >= o) ? sd[t - o] : 0;
        __syncthreads();
        sd[t] += x;
        __syncthreads();
    }
    if (i < n) scanTmp[i] = sd[t];
    if (t == 255) partials[blockIdx.x] = sd[255];
}

// ---------------- scan stage 2: exclusive scan of block partials (NB <= 256) ----------------
__global__ __launch_bounds__(256) void scanpartials_k(int* __restrict__ partials, int nb) {
    __shared__ int sd[256];
    int t = threadIdx.x;
    int v = (t < nb) ? partials[t] : 0;
    sd[t] = v;
    __syncthreads();
    for (int o = 1; o < 256; o <<= 1) {
        int x = (t >= o) ? sd[t - o] : 0;
        __syncthreads();
        sd[t] += x;
        __syncthreads();
    }
    if (t < nb) partials[t] = sd[t] - v;  // exclusive
}

// ---------------- scan stage 3: segStart (exclusive), cursor ----------------
__global__ void addback_k(const int* __restrict__ scanTmp, const int* __restrict__ partials,
                          const unsigned long long* __restrict__ packed,
                          int* __restrict__ segStart, int* __restrict__ cursor,
                          int n, int E) {
    int i = blockIdx.x * 256 + threadIdx.x;
    if (i < n) {
        int cnt = (int)(packed[i] >> 40);
        int st = scanTmp[i] + partials[i >> 8] - cnt;
        segStart[i] = st;
        cursor[i] = st;
    }
    if (i == 0) segStart[n] = E;
}

// ---------------- reorder: one packed int2 scattered store per edge ----------------
__global__ void reorder_k(const int* __restrict__ row, const int* __restrict__ col,
                          const float* __restrict__ P, const float* __restrict__ dis,
                          int* __restrict__ cursor, int2* __restrict__ sedge, int E) {
    int e = blockIdx.x * 256 + threadIdx.x;
    if (e < E) {
        int r = row[e], c = col[e];
        float s = 1.0f / (1.0f + expf(-P[e]));
        float nv = dis[r] * s * dis[c];
        int p = atomicAdd(&cursor[c], 1);
        sedge[p] = make_int2(r, __float_as_int(nv));
    }
}

// ---------------- fold tail linear ops: Wc = W3 @ Wl, bc = b3 @ Wl + bl ----------------
// NOTE: needs 64*N_CLASSES = 640 threads -> launched with 3 blocks of 256.
__global__ void fold_k(const float* __restrict__ W3, const float* __restrict__ b3,
                       const float* __restrict__ Wl, const float* __restrict__ bl,
                       float* __restrict__ Wc, float* __restrict__ bc) {
    int t = blockIdx.x * 256 + threadIdx.x;
    if (t < 64 * N_CLASSES) {
        int k = t / N_CLASSES, c = t % N_CLASSES;
        float acc = 0.0f;
        for (int m = 0; m < 64; ++m) acc += W3[k * 64 + m] * Wl[m * N_CLASSES + c];
        Wc[t] = acc;
    }
    if (t < N_CLASSES) {
        float acc = bl[t];
        for (int m = 0; m < 64; ++m) acc += b3[m] * Wl[m * N_CLASSES + t];
        bc[t] = acc;
    }
}

// ---------------- fused layer: agg (self-loop + CSR gather) -> [@W + b -> relu] ----------------
// agg(h@W) == agg(h)@W. One wave per 8 nodes; lane = feature.
// MODE 1: W held in LDS (16 KB/block, loaded once, reused by 32 nodes); epilogue
//         batches all 8 nodes per k: 1 conflict-free ds_read + 8 readlane + 8 fma.
// MODE 0: pure aggregation (tail folded into classifier).
template <int MODE>
__global__ __launch_bounds__(256) void agg_mm_k(const float* __restrict__ h,
                                                const int2* __restrict__ sedge,
                                                const int* __restrict__ segStart,
                                                const float* __restrict__ dis,
                                                const float* __restrict__ W,
                                                const float* __restrict__ b,
                                                float* __restrict__ out, int n) {
    __shared__ float Wlds[MODE ? 64 * 64 : 1];
    int tid = threadIdx.x;
    if (MODE == 1) {
        for (int i = tid; i < 64 * 64; i += 256) Wlds[i] = W[i];
        __syncthreads();
    }
    int wid = blockIdx.x * 4 + (tid >> 6);
    int lane = tid & 63;
    int nodeBase = wid * 8;
    if (nodeBase >= n) return;

    float acc[8];
#pragma unroll
    for (int i = 0; i < 8; ++i) {
        int node = nodeBase + i;
        float a = 0.0f;
        if (node < n) {
            float d = dis[node];
            a = d * d * h[node * 64 + lane];  // self loop (weight 1)
            int start = segStart[node];
            int end = segStart[node + 1];
            for (int base = start; base < end; base += 64) {
                int m = end - base; if (m > 64) m = 64;
                int2 ed = make_int2(0, 0);
                if (lane < m) ed = sedge[base + lane];
                for (int j = 0; j < m; ++j) {
                    int rr = __shfl(ed.x, j);
                    float nn = __int_as_float(__shfl(ed.y, j));
                    a += nn * h[rr * 64 + lane];
                }
            }
        }
        acc[i] = a;
    }

    if (MODE == 1) {
        float o[8];
        float bv = b[lane];
#pragma unroll
        for (int i = 0; i < 8; ++i) o[i] = bv;
#pragma unroll
        for (int k = 0; k < 64; ++k) {
            float wk = Wlds[k * 64 + lane];  // 2 lanes/bank: conflict-free
#pragma unroll
            for (int i = 0; i < 8; ++i) {
                float av = __int_as_float(
                    __builtin_amdgcn_readlane(__float_as_int(acc[i]), k));
                o[i] = fmaf(av, wk, o[i]);
            }
        }
#pragma unroll
        for (int i = 0; i < 8; ++i) {
            int node = nodeBase + i;
            if (node < n) out[node * 64 + lane] = fmaxf(o[i], 0.0f);
        }
    } else {
#pragma unroll
        for (int i = 0; i < 8; ++i) {
            int node = nodeBase + i;
            if (node < n) out[node * 64 + lane] = acc[i];
        }
    }
}

// ---------------- pooling phase A: segmented partial sums, flush on graph change ----------------
__global__ __launch_bounds__(256) void poolpart_k(const float* __restrict__ h,
                                                  const int* __restrict__ batch,
                                                  float* __restrict__ sums,
                                                  float* __restrict__ cntG, int n) {
    int wave = threadIdx.x >> 6, lane = threadIdx.x & 63;
    int base = blockIdx.x * 128 + wave * 32;
    if (base >= n) return;
    int end = base + 32; if (end > n) end = n;
    int g = batch[base];
    float acc = 0.0f;
    int run = 0;
    for (int i = base; i < end; ++i) {
        int gi = batch[i];
        if (gi != g) {
            atomicAdd(&sums[g * 64 + lane], acc);
            if (lane == 0) atomicAdd(&cntG[g], (float)run);
            g = gi; acc = 0.0f; run = 0;
        }
        acc += h[i * 64 + lane];
        ++run;
    }
    atomicAdd(&sums[g * 64 + lane], acc);
    if (lane == 0) atomicAdd(&cntG[g], (float)run);
}

// ---------------- pooling phase B: mean + folded classifier (Wc, bc) ----------------
__global__ void classify_k(const float* __restrict__ sums, const float* __restrict__ cntG,
                           const float* __restrict__ Wc, const float* __restrict__ bc,
                           float* __restrict__ out) {
    __shared__ float pooled[64];
    int g = blockIdx.x;
    int t = threadIdx.x;  // 64
    float inv = 1.0f / fmaxf(cntG[g], 1.0f);
    pooled[t] = sums[g * 64 + t] * inv;
    __syncthreads();
    if (t < N_CLASSES) {
        float acc = bc[t];
        for (int k = 0; k < 64; ++k) acc += pooled[k] * Wc[k * N_CLASSES + t];
        out[g * N_CLASSES + t] = acc;
    }
}

extern "C" void kernel_launch(void* const* d_in, const int* in_sizes, int n_in,
                              void* d_out, int out_size, void* d_ws, size_t ws_size,
                              hipStream_t stream) {
    const float* x     = (const float*)d_in[0];
    const int*   eidx  = (const int*)d_in[1];
    const int*   batch = (const int*)d_in[2];
    const float* P     = (const float*)d_in[3];
    const float* W1 = (const float*)d_in[4];
    const float* b1 = (const float*)d_in[5];
    const float* W2 = (const float*)d_in[6];
    const float* b2 = (const float*)d_in[7];
    const float* W3 = (const float*)d_in[8];
    const float* b3 = (const float*)d_in[9];
    const float* Wl = (const float*)d_in[10];
    const float* bl = (const float*)d_in[11];
    float* out = (float*)d_out;

    const int N = in_sizes[2];      // 50000
    const int E = in_sizes[3];      // 800000
    const int* row = eidx;
    const int* col = eidx + E;

    // workspace layout
    char* p = (char*)d_ws;
    unsigned long long* packed = (unsigned long long*)p; p += (size_t)N * 8;
    float* dis      = (float*)p; p += (size_t)N * 4;
    int*   scanTmp  = (int*)p;   p += (size_t)N * 4;
    int*   segStart = (int*)p;   p += (size_t)(N + 1) * 4;
    int*   cursor   = (int*)p;   p += (size_t)N * 4;
    int*   partials = (int*)p;   p += 256 * 4;
    float* sums     = (float*)p; p += (size_t)N_GRAPHS * 64 * 4;
    float* cntG     = (float*)p; p += (size_t)N_GRAPHS * 4;
    float* Wc       = (float*)p; p += (size_t)64 * N_CLASSES * 4;
    float* bc       = (float*)p; p += (size_t)N_CLASSES * 4;
    int2*  sedge    = (int2*)p;  p += (size_t)E * 8;
    float* bufA     = (float*)p; p += (size_t)N * 64 * 4;
    float* bufB     = (float*)p; p += (size_t)N * 64 * 4;

    dim3 blk(256);
    int nodeG = (N + 255) / 256;       // 196
    int edgeG = (E + 255) / 256;       // 3125
    int NB = nodeG;

    init_k<<<nodeG, blk, 0, stream>>>(packed, sums, cntG, N);
    hist_k<<<edgeG, blk, 0, stream>>>(P, col, packed, E);
    dis_k<<<nodeG, blk, 0, stream>>>(packed, dis, N);
    blockscan_k<<<NB, blk, 0, stream>>>(packed, scanTmp, partials, N);
    scanpartials_k<<<1, blk, 0, stream>>>(partials, NB);
    addback_k<<<nodeG, blk, 0, stream>>>(scanTmp, partials, packed, segStart, cursor, N, E);
    reorder_k<<<edgeG, blk, 0, stream>>>(row, col, P, dis, cursor, sedge, E);
    fold_k<<<(64 * N_CLASSES + 255) / 256, blk, 0, stream>>>(W3, b3, Wl, bl, Wc, bc);

    int aggG = (N + 31) / 32;  // 8 nodes/wave, 4 waves/block

    // Layer 1: h1 = relu(agg(x) @ W1 + b1)
    agg_mm_k<1><<<aggG, blk, 0, stream>>>(x, sedge, segStart, dis, W1, b1, bufA, N);
    // Layer 2: h2 = relu(agg(h1) @ W2 + b2)
    agg_mm_k<1><<<aggG, blk, 0, stream>>>(bufA, sedge, segStart, dis, W2, b2, bufB, N);
    // Layer 3 (pure agg; W3/b3 folded into classifier)
    agg_mm_k<0><<<aggG, blk, 0, stream>>>(bufB, sedge, segStart, dis, nullptr, nullptr, bufA, N);

    // pool + folded classifier
    int poolG = (N + 127) / 128;
    poolpart_k<<<poolG, blk, 0, stream>>>(bufA, batch, sums, cntG, N);
    classify_k<<<N_GRAPHS, dim3(64), 0, stream>>>(sums, cntG, Wc, bc, out);
}

// Round 8
// 392.200 us; speedup vs baseline: 1.2902x; 1.2902x over previous
//
#include <hip/hip_runtime.h>
#include <hip/hip_bf16.h>
#include <math.h>

#define N_GRAPHS 64
#define N_CLASSES 10
#define FIXSCALE 1048576.0f  // 2^20 fixed-point scale for packed degree sum

// ---------------- init: zero packed hist + pooling buffers ----------------
__global__ void init_k(unsigned long long* __restrict__ packed,
                       float* __restrict__ sums, float* __restrict__ cntG, int n) {
    int i = blockIdx.x * 256 + threadIdx.x;
    if (i < n) packed[i] = 0ull;
    if (i < N_GRAPHS * 64) sums[i] = 0.0f;
    if (i < N_GRAPHS) cntG[i] = 0.0f;
}

// ---------------- one 64-bit atomic per edge: count<<40 | fix(sigmoid(P)) ----------------
__global__ void hist_k(const float* __restrict__ P, const int* __restrict__ col,
                       unsigned long long* __restrict__ packed, int E) {
    int e = blockIdx.x * 256 + threadIdx.x;
    if (e < E) {
        float s = 1.0f / (1.0f + expf(-P[e]));
        unsigned long long v =
            (1ull << 40) | (unsigned long long)(s * FIXSCALE + 0.5f);
        atomicAdd(&packed[col[e]], v);
    }
}

// ---------------- dis = (1 + sum_w)^-0.5 from packed ----------------
__global__ void dis_k(const unsigned long long* __restrict__ packed,
                      float* __restrict__ dis, int n) {
    int i = blockIdx.x * 256 + threadIdx.x;
    if (i < n) {
        float deg = 1.0f + (float)(packed[i] & ((1ull << 40) - 1)) * (1.0f / FIXSCALE);
        dis[i] = 1.0f / sqrtf(deg);
    }
}

// ---------------- scan stage 1: per-block inclusive scan of counts ----------------
__global__ __launch_bounds__(256) void blockscan_k(const unsigned long long* __restrict__ packed,
                                                   int* __restrict__ scanTmp,
                                                   int* __restrict__ partials, int n) {
    __shared__ int sd[256];
    int t = threadIdx.x;
    int i = blockIdx.x * 256 + t;
    int v = (i < n) ? (int)(packed[i] >> 40) : 0;
    sd[t] = v;
    __syncthreads();
    for (int o = 1; o < 256; o <<= 1) {
        int x = (t >= o) ? sd[t - o] : 0;
        __syncthreads();
        sd[t] += x;
        __syncthreads();
    }
    if (i < n) scanTmp[i] = sd[t];
    if (t == 255) partials[blockIdx.x] = sd[255];
}

// ---------------- scan stage 2: exclusive scan of block partials (NB <= 256) ----------------
__global__ __launch_bounds__(256) void scanpartials_k(int* __restrict__ partials, int nb) {
    __shared__ int sd[256];
    int t = threadIdx.x;
    int v = (t < nb) ? partials[t] : 0;
    sd[t] = v;
    __syncthreads();
    for (int o = 1; o < 256; o <<= 1) {
        int x = (t >= o) ? sd[t - o] : 0;
        __syncthreads();
        sd[t] += x;
        __syncthreads();
    }
    if (t < nb) partials[t] = sd[t] - v;  // exclusive
}

// ---------------- scan stage 3: segStart (exclusive), cursor ----------------
__global__ void addback_k(const int* __restrict__ scanTmp, const int* __restrict__ partials,
                          const unsigned long long* __restrict__ packed,
                          int* __restrict__ segStart, int* __restrict__ cursor,
                          int n, int E) {
    int i = blockIdx.x * 256 + threadIdx.x;
    if (i < n) {
        int cnt = (int)(packed[i] >> 40);
        int st = scanTmp[i] + partials[i >> 8] - cnt;
        segStart[i] = st;
        cursor[i] = st;
    }
    if (i == 0) segStart[n] = E;
}

// ---------------- reorder: one packed int2 scattered store per edge ----------------
__global__ void reorder_k(const int* __restrict__ row, const int* __restrict__ col,
                          const float* __restrict__ P, const float* __restrict__ dis,
                          int* __restrict__ cursor, int2* __restrict__ sedge, int E) {
    int e = blockIdx.x * 256 + threadIdx.x;
    if (e < E) {
        int r = row[e], c = col[e];
        float s = 1.0f / (1.0f + expf(-P[e]));
        float nv = dis[r] * s * dis[c];
        int p = atomicAdd(&cursor[c], 1);
        sedge[p] = make_int2(r, __float_as_int(nv));
    }
}

// ---------------- fold tail linear ops: Wc = W3 @ Wl, bc = b3 @ Wl + bl ----------------
// NOTE: needs 64*N_CLASSES = 640 threads -> launched with 3 blocks of 256.
__global__ void fold_k(const float* __restrict__ W3, const float* __restrict__ b3,
                       const float* __restrict__ Wl, const float* __restrict__ bl,
                       float* __restrict__ Wc, float* __restrict__ bc) {
    int t = blockIdx.x * 256 + threadIdx.x;
    if (t < 64 * N_CLASSES) {
        int k = t / N_CLASSES, c = t % N_CLASSES;
        float acc = 0.0f;
        for (int m = 0; m < 64; ++m) acc += W3[k * 64 + m] * Wl[m * N_CLASSES + c];
        Wc[t] = acc;
    }
    if (t < N_CLASSES) {
        float acc = bl[t];
        for (int m = 0; m < 64; ++m) acc += b3[m] * Wl[m * N_CLASSES + t];
        bc[t] = acc;
    }
}

// ---------------- fused layer: agg (self-loop + CSR gather) -> [@W + b -> relu] ----------------
// agg(h@W) == agg(h)@W. ONE node per wave (12500 blocks: max resident waves for
// the latency-bound gather — 8-node batching halved effective BW, round 6/7).
// MODE 1: W in LDS; per-node epilogue: 64x (ds_read + readlane + fma).
// MODE 0: pure aggregation (tail folded into classifier).
template <int MODE>
__global__ __launch_bounds__(256) void agg_mm_k(const float* __restrict__ h,
                                                const int2* __restrict__ sedge,
                                                const int* __restrict__ segStart,
                                                const float* __restrict__ dis,
                                                const float* __restrict__ W,
                                                const float* __restrict__ b,
                                                float* __restrict__ out, int n) {
    __shared__ float Wlds[MODE ? 64 * 64 : 1];
    int tid = threadIdx.x;
    if (MODE == 1) {
        for (int i = tid; i < 64 * 64; i += 256) Wlds[i] = W[i];
        __syncthreads();
    }
    int node = blockIdx.x * 4 + (tid >> 6);
    if (node >= n) return;
    int lane = tid & 63;

    float bv = (MODE == 1) ? b[lane] : 0.0f;
    float d = dis[node];
    float acc = d * d * h[node * 64 + lane];  // self loop (weight 1)
    int start = segStart[node];
    int end = segStart[node + 1];
    for (int base = start; base < end; base += 64) {
        int m = end - base; if (m > 64) m = 64;
        int2 ed = make_int2(0, 0);
        if (lane < m) ed = sedge[base + lane];
        for (int j = 0; j < m; ++j) {
            int rr = __shfl(ed.x, j);
            float nn = __int_as_float(__shfl(ed.y, j));
            acc += nn * h[rr * 64 + lane];
        }
    }

    if (MODE == 1) {
        float o = bv;
#pragma unroll
        for (int k = 0; k < 64; ++k) {
            float wk = Wlds[k * 64 + lane];  // 2 lanes/bank: conflict-free
            float av = __int_as_float(
                __builtin_amdgcn_readlane(__float_as_int(acc), k));
            o = fmaf(av, wk, o);
        }
        out[node * 64 + lane] = fmaxf(o, 0.0f);
    } else {
        out[node * 64 + lane] = acc;
    }
}

// ---------------- pooling phase A: segmented partial sums, flush on graph change ----------------
__global__ __launch_bounds__(256) void poolpart_k(const float* __restrict__ h,
                                                  const int* __restrict__ batch,
                                                  float* __restrict__ sums,
                                                  float* __restrict__ cntG, int n) {
    int wave = threadIdx.x >> 6, lane = threadIdx.x & 63;
    int base = blockIdx.x * 128 + wave * 32;
    if (base >= n) return;
    int end = base + 32; if (end > n) end = n;
    int g = batch[base];
    float acc = 0.0f;
    int run = 0;
    for (int i = base; i < end; ++i) {
        int gi = batch[i];
        if (gi != g) {
            atomicAdd(&sums[g * 64 + lane], acc);
            if (lane == 0) atomicAdd(&cntG[g], (float)run);
            g = gi; acc = 0.0f; run = 0;
        }
        acc += h[i * 64 + lane];
        ++run;
    }
    atomicAdd(&sums[g * 64 + lane], acc);
    if (lane == 0) atomicAdd(&cntG[g], (float)run);
}

// ---------------- pooling phase B: mean + folded classifier (Wc, bc) ----------------
__global__ void classify_k(const float* __restrict__ sums, const float* __restrict__ cntG,
                           const float* __restrict__ Wc, const float* __restrict__ bc,
                           float* __restrict__ out) {
    __shared__ float pooled[64];
    int g = blockIdx.x;
    int t = threadIdx.x;  // 64
    float inv = 1.0f / fmaxf(cntG[g], 1.0f);
    pooled[t] = sums[g * 64 + t] * inv;
    __syncthreads();
    if (t < N_CLASSES) {
        float acc = bc[t];
        for (int k = 0; k < 64; ++k) acc += pooled[k] * Wc[k * N_CLASSES + t];
        out[g * N_CLASSES + t] = acc;
    }
}

extern "C" void kernel_launch(void* const* d_in, const int* in_sizes, int n_in,
                              void* d_out, int out_size, void* d_ws, size_t ws_size,
                              hipStream_t stream) {
    const float* x     = (const float*)d_in[0];
    const int*   eidx  = (const int*)d_in[1];
    const int*   batch = (const int*)d_in[2];
    const float* P     = (const float*)d_in[3];
    const float* W1 = (const float*)d_in[4];
    const float* b1 = (const float*)d_in[5];
    const float* W2 = (const float*)d_in[6];
    const float* b2 = (const float*)d_in[7];
    const float* W3 = (const float*)d_in[8];
    const float* b3 = (const float*)d_in[9];
    const float* Wl = (const float*)d_in[10];
    const float* bl = (const float*)d_in[11];
    float* out = (float*)d_out;

    const int N = in_sizes[2];      // 50000
    const int E = in_sizes[3];      // 800000
    const int* row = eidx;
    const int* col = eidx + E;

    // workspace layout
    char* p = (char*)d_ws;
    unsigned long long* packed = (unsigned long long*)p; p += (size_t)N * 8;
    float* dis      = (float*)p; p += (size_t)N * 4;
    int*   scanTmp  = (int*)p;   p += (size_t)N * 4;
    int*   segStart = (int*)p;   p += (size_t)(N + 1) * 4;
    int*   cursor   = (int*)p;   p += (size_t)N * 4;
    int*   partials = (int*)p;   p += 256 * 4;
    float* sums     = (float*)p; p += (size_t)N_GRAPHS * 64 * 4;
    float* cntG     = (float*)p; p += (size_t)N_GRAPHS * 4;
    float* Wc       = (float*)p; p += (size_t)64 * N_CLASSES * 4;
    float* bc       = (float*)p; p += (size_t)N_CLASSES * 4;
    int2*  sedge    = (int2*)p;  p += (size_t)E * 8;
    float* bufA     = (float*)p; p += (size_t)N * 64 * 4;
    float* bufB     = (float*)p; p += (size_t)N * 64 * 4;

    dim3 blk(256);
    int nodeG = (N + 255) / 256;       // 196
    int edgeG = (E + 255) / 256;       // 3125
    int NB = nodeG;

    init_k<<<nodeG, blk, 0, stream>>>(packed, sums, cntG, N);
    hist_k<<<edgeG, blk, 0, stream>>>(P, col, packed, E);
    dis_k<<<nodeG, blk, 0, stream>>>(packed, dis, N);
    blockscan_k<<<NB, blk, 0, stream>>>(packed, scanTmp, partials, N);
    scanpartials_k<<<1, blk, 0, stream>>>(partials, NB);
    addback_k<<<nodeG, blk, 0, stream>>>(scanTmp, partials, packed, segStart, cursor, N, E);
    reorder_k<<<edgeG, blk, 0, stream>>>(row, col, P, dis, cursor, sedge, E);
    fold_k<<<(64 * N_CLASSES + 255) / 256, blk, 0, stream>>>(W3, b3, Wl, bl, Wc, bc);

    int aggG = (N + 3) / 4;  // 1 node per wave, 4 waves/block

    // Layer 1: h1 = relu(agg(x) @ W1 + b1)
    agg_mm_k<1><<<aggG, blk, 0, stream>>>(x, sedge, segStart, dis, W1, b1, bufA, N);
    // Layer 2: h2 = relu(agg(h1) @ W2 + b2)
    agg_mm_k<1><<<aggG, blk, 0, stream>>>(bufA, sedge, segStart, dis, W2, b2, bufB, N);
    // Layer 3 (pure agg; W3/b3 folded into classifier)
    agg_mm_k<0><<<aggG, blk, 0, stream>>>(bufB, sedge, segStart, dis, nullptr, nullptr, bufA, N);

    // pool + folded classifier
    int poolG = (N + 127) / 128;
    poolpart_k<<<poolG, blk, 0, stream>>>(bufA, batch, sums, cntG, N);
    classify_k<<<N_GRAPHS, dim3(64), 0, stream>>>(sums, cntG, Wc, bc, out);
}

// Round 9
// 351.750 us; speedup vs baseline: 1.4386x; 1.1150x over previous
//
#include <hip/hip_runtime.h>
#include <hip/hip_bf16.h>
#include <math.h>

#define N_GRAPHS 64
#define N_CLASSES 10
#define FIXSCALE 1048576.0f  // 2^20 fixed-point scale for packed degree sum

typedef __hip_bfloat16 bf16;

// ---------------- init: zero packed hist + pool buffers, convert x -> bf16 ----------------
__global__ void init_k(unsigned long long* __restrict__ packed,
                       float* __restrict__ sums, float* __restrict__ cntG,
                       const float* __restrict__ x, bf16* __restrict__ xbf, int n) {
    int i = blockIdx.x * 256 + threadIdx.x;
    if (i < n) packed[i] = 0ull;
    if (i < N_GRAPHS * 64) sums[i] = 0.0f;
    if (i < N_GRAPHS) cntG[i] = 0.0f;
    if (i < n * 64) xbf[i] = __float2bfloat16(x[i]);
}

// ---------------- one 64-bit atomic per edge: count<<40 | fix(sigmoid(P)) ----------------
__global__ void hist_k(const float* __restrict__ P, const int* __restrict__ col,
                       unsigned long long* __restrict__ packed, int E) {
    int e = blockIdx.x * 256 + threadIdx.x;
    if (e < E) {
        float s = 1.0f / (1.0f + expf(-P[e]));
        unsigned long long v =
            (1ull << 40) | (unsigned long long)(s * FIXSCALE + 0.5f);
        atomicAdd(&packed[col[e]], v);
    }
}

// ---------------- scan stage 1 (+ fused dis = deg^-0.5) ----------------
__global__ __launch_bounds__(256) void blockscan_k(const unsigned long long* __restrict__ packed,
                                                   float* __restrict__ dis,
                                                   int* __restrict__ scanTmp,
                                                   int* __restrict__ partials, int n) {
    __shared__ int sd[256];
    int t = threadIdx.x;
    int i = blockIdx.x * 256 + t;
    int v = 0;
    if (i < n) {
        unsigned long long pk = packed[i];
        float deg = 1.0f + (float)(pk & ((1ull << 40) - 1)) * (1.0f / FIXSCALE);
        dis[i] = 1.0f / sqrtf(deg);
        v = (int)(pk >> 40);
    }
    sd[t] = v;
    __syncthreads();
    for (int o = 1; o < 256; o <<= 1) {
        int x = (t >= o) ? sd[t - o] : 0;
        __syncthreads();
        sd[t] += x;
        __syncthreads();
    }
    if (i < n) scanTmp[i] = sd[t];
    if (t == 255) partials[blockIdx.x] = sd[255];
}

// ---------------- scan stage 2: exclusive scan of block partials (NB <= 256) ----------------
__global__ __launch_bounds__(256) void scanpartials_k(int* __restrict__ partials, int nb) {
    __shared__ int sd[256];
    int t = threadIdx.x;
    int v = (t < nb) ? partials[t] : 0;
    sd[t] = v;
    __syncthreads();
    for (int o = 1; o < 256; o <<= 1) {
        int x = (t >= o) ? sd[t - o] : 0;
        __syncthreads();
        sd[t] += x;
        __syncthreads();
    }
    if (t < nb) partials[t] = sd[t] - v;  // exclusive
}

// ---------------- scan stage 3: segStart (exclusive), cursor ----------------
__global__ void addback_k(const int* __restrict__ scanTmp, const int* __restrict__ partials,
                          const unsigned long long* __restrict__ packed,
                          int* __restrict__ segStart, int* __restrict__ cursor,
                          int n, int E) {
    int i = blockIdx.x * 256 + threadIdx.x;
    if (i < n) {
        int cnt = (int)(packed[i] >> 40);
        int st = scanTmp[i] + partials[i >> 8] - cnt;
        segStart[i] = st;
        cursor[i] = st;
    }
    if (i == 0) segStart[n] = E;
}

// ---------------- reorder: one packed int2 scattered store per edge ----------------
__global__ void reorder_k(const int* __restrict__ row, const int* __restrict__ col,
                          const float* __restrict__ P, const float* __restrict__ dis,
                          int* __restrict__ cursor, int2* __restrict__ sedge, int E) {
    int e = blockIdx.x * 256 + threadIdx.x;
    if (e < E) {
        int r = row[e], c = col[e];
        float s = 1.0f / (1.0f + expf(-P[e]));
        float nv = dis[r] * s * dis[c];
        int p = atomicAdd(&cursor[c], 1);
        sedge[p] = make_int2(r, __float_as_int(nv));
    }
}

// ---------------- fold tail linear ops: Wc = W3 @ Wl, bc = b3 @ Wl + bl ----------------
// needs 640 threads -> launched with 3 blocks of 256.
__global__ void fold_k(const float* __restrict__ W3, const float* __restrict__ b3,
                       const float* __restrict__ Wl, const float* __restrict__ bl,
                       float* __restrict__ Wc, float* __restrict__ bc) {
    int t = blockIdx.x * 256 + threadIdx.x;
    if (t < 64 * N_CLASSES) {
        int k = t / N_CLASSES, c = t % N_CLASSES;
        float acc = 0.0f;
        for (int m = 0; m < 64; ++m) acc += W3[k * 64 + m] * Wl[m * N_CLASSES + c];
        Wc[t] = acc;
    }
    if (t < N_CLASSES) {
        float acc = bl[t];
        for (int m = 0; m < 64; ++m) acc += b3[m] * Wl[m * N_CLASSES + t];
        bc[t] = acc;
    }
}

// ---------------- fused layer: agg (f32 self + bf16 CSR gather) -> [@W + b -> relu] ----------------
// agg(h@W) == agg(h)@W. One node per wave (max resident waves for latency-bound
// gather — proven round 8). Neighbor rows read as bf16 (128 B/row: halves gather
// traffic); self term, epilogue, outputs stay f32. MODE 1 also emits a bf16 copy
// for the next layer's gather. MODE 0: pure agg, f32 out only (tail folded).
template <int MODE>
__global__ __launch_bounds__(256) void agg_mm_k(const float* __restrict__ hf,
                                                const bf16* __restrict__ hb,
                                                const int2* __restrict__ sedge,
                                                const int* __restrict__ segStart,
                                                const float* __restrict__ dis,
                                                const float* __restrict__ W,
                                                const float* __restrict__ b,
                                                float* __restrict__ out,
                                                bf16* __restrict__ out_bf, int n) {
    __shared__ float Wlds[MODE ? 64 * 64 : 1];
    int tid = threadIdx.x;
    if (MODE == 1) {
        for (int i = tid; i < 64 * 64; i += 256) Wlds[i] = W[i];
        __syncthreads();
    }
    int node = blockIdx.x * 4 + (tid >> 6);
    if (node >= n) return;
    int lane = tid & 63;

    float bv = (MODE == 1) ? b[lane] : 0.0f;
    float d = dis[node];
    float acc = d * d * hf[node * 64 + lane];  // self loop (weight 1), full f32
    int start = segStart[node];
    int end = segStart[node + 1];
    for (int base = start; base < end; base += 64) {
        int m = end - base; if (m > 64) m = 64;
        int2 ed = make_int2(0, 0);
        if (lane < m) ed = sedge[base + lane];
        float a0 = 0.0f, a1 = 0.0f;
        int j = 0;
        for (; j + 1 < m; j += 2) {  // dual accumulators: 2 gathers in flight
            int r0 = __shfl(ed.x, j);
            float n0 = __int_as_float(__shfl(ed.y, j));
            int r1 = __shfl(ed.x, j + 1);
            float n1 = __int_as_float(__shfl(ed.y, j + 1));
            a0 = fmaf(n0, __bfloat162float(hb[r0 * 64 + lane]), a0);
            a1 = fmaf(n1, __bfloat162float(hb[r1 * 64 + lane]), a1);
        }
        if (j < m) {
            int r0 = __shfl(ed.x, j);
            float n0 = __int_as_float(__shfl(ed.y, j));
            a0 = fmaf(n0, __bfloat162float(hb[r0 * 64 + lane]), a0);
        }
        acc += a0 + a1;
    }

    if (MODE == 1) {
        float o = bv;
#pragma unroll
        for (int k = 0; k < 64; ++k) {
            float wk = Wlds[k * 64 + lane];  // 2 lanes/bank: conflict-free
            float av = __int_as_float(
                __builtin_amdgcn_readlane(__float_as_int(acc), k));
            o = fmaf(av, wk, o);
        }
        o = fmaxf(o, 0.0f);
        out[node * 64 + lane] = o;
        out_bf[node * 64 + lane] = __float2bfloat16(o);
    } else {
        out[node * 64 + lane] = acc;
    }
}

// ---------------- pooling phase A: segmented partial sums, flush on graph change ----------------
__global__ __launch_bounds__(256) void poolpart_k(const float* __restrict__ h,
                                                  const int* __restrict__ batch,
                                                  float* __restrict__ sums,
                                                  float* __restrict__ cntG, int n) {
    int wave = threadIdx.x >> 6, lane = threadIdx.x & 63;
    int base = blockIdx.x * 128 + wave * 32;
    if (base >= n) return;
    int end = base + 32; if (end > n) end = n;
    int g = batch[base];
    float acc = 0.0f;
    int run = 0;
    for (int i = base; i < end; ++i) {
        int gi = batch[i];
        if (gi != g) {
            atomicAdd(&sums[g * 64 + lane], acc);
            if (lane == 0) atomicAdd(&cntG[g], (float)run);
            g = gi; acc = 0.0f; run = 0;
        }
        acc += h[i * 64 + lane];
        ++run;
    }
    atomicAdd(&sums[g * 64 + lane], acc);
    if (lane == 0) atomicAdd(&cntG[g], (float)run);
}

// ---------------- pooling phase B: mean + folded classifier (Wc, bc) ----------------
__global__ void classify_k(const float* __restrict__ sums, const float* __restrict__ cntG,
                           const float* __restrict__ Wc, const float* __restrict__ bc,
                           float* __restrict__ out) {
    __shared__ float pooled[64];
    int g = blockIdx.x;
    int t = threadIdx.x;  // 64
    float inv = 1.0f / fmaxf(cntG[g], 1.0f);
    pooled[t] = sums[g * 64 + t] * inv;
    __syncthreads();
    if (t < N_CLASSES) {
        float acc = bc[t];
        for (int k = 0; k < 64; ++k) acc += pooled[k] * Wc[k * N_CLASSES + t];
        out[g * N_CLASSES + t] = acc;
    }
}

extern "C" void kernel_launch(void* const* d_in, const int* in_sizes, int n_in,
                              void* d_out, int out_size, void* d_ws, size_t ws_size,
                              hipStream_t stream) {
    const float* x     = (const float*)d_in[0];
    const int*   eidx  = (const int*)d_in[1];
    const int*   batch = (const int*)d_in[2];
    const float* P     = (const float*)d_in[3];
    const float* W1 = (const float*)d_in[4];
    const float* b1 = (const float*)d_in[5];
    const float* W2 = (const float*)d_in[6];
    const float* b2 = (const float*)d_in[7];
    const float* W3 = (const float*)d_in[8];
    const float* b3 = (const float*)d_in[9];
    const float* Wl = (const float*)d_in[10];
    const float* bl = (const float*)d_in[11];
    float* out = (float*)d_out;

    const int N = in_sizes[2];      // 50000
    const int E = in_sizes[3];      // 800000
    const int* row = eidx;
    const int* col = eidx + E;

    // workspace layout
    char* p = (char*)d_ws;
    unsigned long long* packed = (unsigned long long*)p; p += (size_t)N * 8;
    float* dis      = (float*)p; p += (size_t)N * 4;
    int*   scanTmp  = (int*)p;   p += (size_t)N * 4;
    int*   segStart = (int*)p;   p += (size_t)(N + 1) * 4;
    int*   cursor   = (int*)p;   p += (size_t)N * 4;
    int*   partials = (int*)p;   p += 256 * 4;
    float* sums     = (float*)p; p += (size_t)N_GRAPHS * 64 * 4;
    float* cntG     = (float*)p; p += (size_t)N_GRAPHS * 4;
    float* Wc       = (float*)p; p += (size_t)64 * N_CLASSES * 4;
    float* bc       = (float*)p; p += (size_t)N_CLASSES * 4;
    int2*  sedge    = (int2*)p;  p += (size_t)E * 8;
    float* bufA     = (float*)p; p += (size_t)N * 64 * 4;
    float* bufB     = (float*)p; p += (size_t)N * 64 * 4;
    bf16*  xbf      = (bf16*)p;  p += (size_t)N * 64 * 2;   // layer-1 gather; reused as bfB
    bf16*  bfA      = (bf16*)p;  p += (size_t)N * 64 * 2;   // h1 bf16
    bf16*  bfB      = xbf;  // layer-2 output bf16 (x_bf dead after layer 1)

    dim3 blk(256);
    int nodeG = (N + 255) / 256;           // 196
    int edgeG = (E + 255) / 256;           // 3125
    int bigG  = (N * 64 + 255) / 256;      // 12500
    int NB = nodeG;

    init_k<<<bigG, blk, 0, stream>>>(packed, sums, cntG, x, xbf, N);
    hist_k<<<edgeG, blk, 0, stream>>>(P, col, packed, E);
    blockscan_k<<<NB, blk, 0, stream>>>(packed, dis, scanTmp, partials, N);
    scanpartials_k<<<1, blk, 0, stream>>>(partials, NB);
    addback_k<<<nodeG, blk, 0, stream>>>(scanTmp, partials, packed, segStart, cursor, N, E);
    reorder_k<<<edgeG, blk, 0, stream>>>(row, col, P, dis, cursor, sedge, E);
    fold_k<<<(64 * N_CLASSES + 255) / 256, blk, 0, stream>>>(W3, b3, Wl, bl, Wc, bc);

    int aggG = (N + 3) / 4;  // 1 node per wave, 4 waves/block

    // Layer 1: h1 = relu(agg(x) @ W1 + b1)   (self f32 from x, gather bf16 from xbf)
    agg_mm_k<1><<<aggG, blk, 0, stream>>>(x, xbf, sedge, segStart, dis, W1, b1, bufA, bfA, N);
    // Layer 2: h2 = relu(agg(h1) @ W2 + b2)
    agg_mm_k<1><<<aggG, blk, 0, stream>>>(bufA, bfA, sedge, segStart, dis, W2, b2, bufB, bfB, N);
    // Layer 3 (pure agg; W3/b3 folded into classifier)
    agg_mm_k<0><<<aggG, blk, 0, stream>>>(bufB, bfB, sedge, segStart, dis, nullptr, nullptr, bufA, nullptr, N);

    // pool + folded classifier
    int poolG = (N + 127) / 128;
    poolpart_k<<<poolG, blk, 0, stream>>>(bufA, batch, sums, cntG, N);
    classify_k<<<N_GRAPHS, dim3(64), 0, stream>>>(sums, cntG, Wc, bc, out);
}

// Round 10
// 323.017 us; speedup vs baseline: 1.5666x; 1.0890x over previous
//
#include <hip/hip_runtime.h>
#include <hip/hip_bf16.h>
#include <math.h>

#define N_GRAPHS 64
#define N_CLASSES 10
#define FIXSCALE 1048576.0f  // 2^20 fixed-point scale for packed degree sum

typedef __hip_bfloat16 bf16;

// ---------------- init: zero packed hist + pool buffers, convert x -> bf16 ----------------
__global__ void init_k(unsigned long long* __restrict__ packed,
                       float* __restrict__ sums, float* __restrict__ cntG,
                       const float* __restrict__ x, bf16* __restrict__ xbf, int n) {
    int i = blockIdx.x * 256 + threadIdx.x;
    if (i < n) packed[i] = 0ull;
    if (i < N_GRAPHS * 64) sums[i] = 0.0f;
    if (i < N_GRAPHS) cntG[i] = 0.0f;
    if (i < n * 64) xbf[i] = __float2bfloat16(x[i]);
}

// ---------------- one 64-bit atomic per edge: count<<40 | fix(sigmoid(P)) ----------------
// The returned old value's count field = this edge's rank within its destination
// segment -> stored coalesced, making the reorder pass atomic-free.
__global__ void hist_k(const float* __restrict__ P, const int* __restrict__ col,
                       unsigned long long* __restrict__ packed,
                       int* __restrict__ rank, int E) {
    int e = blockIdx.x * 256 + threadIdx.x;
    if (e < E) {
        float s = 1.0f / (1.0f + expf(-P[e]));
        unsigned long long v =
            (1ull << 40) | (unsigned long long)(s * FIXSCALE + 0.5f);
        unsigned long long old = atomicAdd(&packed[col[e]], v);
        rank[e] = (int)(old >> 40);
    }
}

// ---------------- scan stage 1 (+ fused dis = deg^-0.5) ----------------
__global__ __launch_bounds__(256) void blockscan_k(const unsigned long long* __restrict__ packed,
                                                   float* __restrict__ dis,
                                                   int* __restrict__ scanTmp,
                                                   int* __restrict__ partials, int n) {
    __shared__ int sd[256];
    int t = threadIdx.x;
    int i = blockIdx.x * 256 + t;
    int v = 0;
    if (i < n) {
        unsigned long long pk = packed[i];
        float deg = 1.0f + (float)(pk & ((1ull << 40) - 1)) * (1.0f / FIXSCALE);
        dis[i] = 1.0f / sqrtf(deg);
        v = (int)(pk >> 40);
    }
    sd[t] = v;
    __syncthreads();
    for (int o = 1; o < 256; o <<= 1) {
        int x = (t >= o) ? sd[t - o] : 0;
        __syncthreads();
        sd[t] += x;
        __syncthreads();
    }
    if (i < n) scanTmp[i] = sd[t];
    if (t == 255) partials[blockIdx.x] = sd[255];
}

// ---------------- scan stage 2: exclusive scan of block partials (NB <= 256) ----------------
__global__ __launch_bounds__(256) void scanpartials_k(int* __restrict__ partials, int nb) {
    __shared__ int sd[256];
    int t = threadIdx.x;
    int v = (t < nb) ? partials[t] : 0;
    sd[t] = v;
    __syncthreads();
    for (int o = 1; o < 256; o <<= 1) {
        int x = (t >= o) ? sd[t - o] : 0;
        __syncthreads();
        sd[t] += x;
        __syncthreads();
    }
    if (t < nb) partials[t] = sd[t] - v;  // exclusive
}

// ---------------- scan stage 3: segStart (exclusive) ----------------
__global__ void addback_k(const int* __restrict__ scanTmp, const int* __restrict__ partials,
                          const unsigned long long* __restrict__ packed,
                          int* __restrict__ segStart, int n, int E) {
    int i = blockIdx.x * 256 + threadIdx.x;
    if (i < n) {
        int cnt = (int)(packed[i] >> 40);
        segStart[i] = scanTmp[i] + partials[i >> 8] - cnt;
    }
    if (i == 0) segStart[n] = E;
}

// ---------------- reorder: atomic-free, pos = segStart[col] + rank ----------------
__global__ void reorder_k(const int* __restrict__ row, const int* __restrict__ col,
                          const float* __restrict__ P, const float* __restrict__ dis,
                          const int* __restrict__ segStart, const int* __restrict__ rank,
                          int2* __restrict__ sedge, int E) {
    int e = blockIdx.x * 256 + threadIdx.x;
    if (e < E) {
        int r = row[e], c = col[e];
        float s = 1.0f / (1.0f + expf(-P[e]));
        float nv = dis[r] * s * dis[c];
        int pos = segStart[c] + rank[e];
        sedge[pos] = make_int2(r, __float_as_int(nv));
    }
}

// ---------------- fold tail linear ops: Wc = W3 @ Wl, bc = b3 @ Wl + bl ----------------
// needs 640 threads -> launched with 3 blocks of 256.
__global__ void fold_k(const float* __restrict__ W3, const float* __restrict__ b3,
                       const float* __restrict__ Wl, const float* __restrict__ bl,
                       float* __restrict__ Wc, float* __restrict__ bc) {
    int t = blockIdx.x * 256 + threadIdx.x;
    if (t < 64 * N_CLASSES) {
        int k = t / N_CLASSES, c = t % N_CLASSES;
        float acc = 0.0f;
        for (int m = 0; m < 64; ++m) acc += W3[k * 64 + m] * Wl[m * N_CLASSES + c];
        Wc[t] = acc;
    }
    if (t < N_CLASSES) {
        float acc = bl[t];
        for (int m = 0; m < 64; ++m) acc += b3[m] * Wl[m * N_CLASSES + t];
        bc[t] = acc;
    }
}

// ---------------- fused layer: agg (f32 self + bf16 CSR gather) -> [@W + b -> relu] ----------------
// One node per wave; node forced wave-uniform (readfirstlane) so the edge loop
// is scalar: sedge[e] becomes an s_load / uniform broadcast — NO per-edge
// shuffles (round 9 spent 2 ds_bpermute per edge). Dual accumulators keep 2
// gathers in flight. MODE 1: W in LDS, readlane-GEMM epilogue + bf16 copy out.
// MODE 0: pure aggregation (tail folded into classifier).
template <int MODE>
__global__ __launch_bounds__(256) void agg_mm_k(const float* __restrict__ hf,
                                                const bf16* __restrict__ hb,
                                                const int2* __restrict__ sedge,
                                                const int* __restrict__ segStart,
                                                const float* __restrict__ dis,
                                                const float* __restrict__ W,
                                                const float* __restrict__ b,
                                                float* __restrict__ out,
                                                bf16* __restrict__ out_bf, int n) {
    __shared__ float Wlds[MODE ? 64 * 64 : 1];
    int tid = threadIdx.x;
    if (MODE == 1) {
        for (int i = tid; i < 64 * 64; i += 256) Wlds[i] = W[i];
        __syncthreads();
    }
    int node = __builtin_amdgcn_readfirstlane(blockIdx.x * 4 + (tid >> 6));
    if (node >= n) return;
    int lane = tid & 63;

    float bv = (MODE == 1) ? b[lane] : 0.0f;
    float d = dis[node];
    float acc = d * d * hf[node * 64 + lane];  // self loop (weight 1), full f32
    int start = segStart[node];
    int end = segStart[node + 1];

    float a0 = 0.0f, a1 = 0.0f;
    int e = start;
    for (; e + 2 <= end; e += 2) {
        int2 e0 = sedge[e];
        int2 e1 = sedge[e + 1];
        a0 = fmaf(__int_as_float(e0.y), __bfloat162float(hb[e0.x * 64 + lane]), a0);
        a1 = fmaf(__int_as_float(e1.y), __bfloat162float(hb[e1.x * 64 + lane]), a1);
    }
    if (e < end) {
        int2 e0 = sedge[e];
        a0 = fmaf(__int_as_float(e0.y), __bfloat162float(hb[e0.x * 64 + lane]), a0);
    }
    acc += a0 + a1;

    if (MODE == 1) {
        float o = bv;
#pragma unroll
        for (int k = 0; k < 64; ++k) {
            float wk = Wlds[k * 64 + lane];  // 2 lanes/bank: conflict-free
            float av = __int_as_float(
                __builtin_amdgcn_readlane(__float_as_int(acc), k));
            o = fmaf(av, wk, o);
        }
        o = fmaxf(o, 0.0f);
        out[node * 64 + lane] = o;
        out_bf[node * 64 + lane] = __float2bfloat16(o);
    } else {
        out[node * 64 + lane] = acc;
    }
}

// ---------------- pooling phase A: segmented partial sums, flush on graph change ----------------
__global__ __launch_bounds__(256) void poolpart_k(const float* __restrict__ h,
                                                  const int* __restrict__ batch,
                                                  float* __restrict__ sums,
                                                  float* __restrict__ cntG, int n) {
    int wave = threadIdx.x >> 6, lane = threadIdx.x & 63;
    int base = blockIdx.x * 128 + wave * 32;
    if (base >= n) return;
    int end = base + 32; if (end > n) end = n;
    int g = batch[base];
    float acc = 0.0f;
    int run = 0;
    for (int i = base; i < end; ++i) {
        int gi = batch[i];
        if (gi != g) {
            atomicAdd(&sums[g * 64 + lane], acc);
            if (lane == 0) atomicAdd(&cntG[g], (float)run);
            g = gi; acc = 0.0f; run = 0;
        }
        acc += h[i * 64 + lane];
        ++run;
    }
    atomicAdd(&sums[g * 64 + lane], acc);
    if (lane == 0) atomicAdd(&cntG[g], (float)run);
}

// ---------------- pooling phase B: mean + folded classifier (Wc, bc) ----------------
__global__ void classify_k(const float* __restrict__ sums, const float* __restrict__ cntG,
                           const float* __restrict__ Wc, const float* __restrict__ bc,
                           float* __restrict__ out) {
    __shared__ float pooled[64];
    int g = blockIdx.x;
    int t = threadIdx.x;  // 64
    float inv = 1.0f / fmaxf(cntG[g], 1.0f);
    pooled[t] = sums[g * 64 + t] * inv;
    __syncthreads();
    if (t < N_CLASSES) {
        float acc = bc[t];
        for (int k = 0; k < 64; ++k) acc += pooled[k] * Wc[k * N_CLASSES + t];
        out[g * N_CLASSES + t] = acc;
    }
}

extern "C" void kernel_launch(void* const* d_in, const int* in_sizes, int n_in,
                              void* d_out, int out_size, void* d_ws, size_t ws_size,
                              hipStream_t stream) {
    const float* x     = (const float*)d_in[0];
    const int*   eidx  = (const int*)d_in[1];
    const int*   batch = (const int*)d_in[2];
    const float* P     = (const float*)d_in[3];
    const float* W1 = (const float*)d_in[4];
    const float* b1 = (const float*)d_in[5];
    const float* W2 = (const float*)d_in[6];
    const float* b2 = (const float*)d_in[7];
    const float* W3 = (const float*)d_in[8];
    const float* b3 = (const float*)d_in[9];
    const float* Wl = (const float*)d_in[10];
    const float* bl = (const float*)d_in[11];
    float* out = (float*)d_out;

    const int N = in_sizes[2];      // 50000
    const int E = in_sizes[3];      // 800000
    const int* row = eidx;
    const int* col = eidx + E;

    // workspace layout
    char* p = (char*)d_ws;
    unsigned long long* packed = (unsigned long long*)p; p += (size_t)N * 8;
    float* dis      = (float*)p; p += (size_t)N * 4;
    int*   scanTmp  = (int*)p;   p += (size_t)N * 4;
    int*   segStart = (int*)p;   p += (size_t)(N + 1) * 4;
    int*   partials = (int*)p;   p += 256 * 4;
    float* sums     = (float*)p; p += (size_t)N_GRAPHS * 64 * 4;
    float* cntG     = (float*)p; p += (size_t)N_GRAPHS * 4;
    float* Wc       = (float*)p; p += (size_t)64 * N_CLASSES * 4;
    float* bc       = (float*)p; p += (size_t)N_CLASSES * 4;
    int*   rank     = (int*)p;   p += (size_t)E * 4;
    int2*  sedge    = (int2*)p;  p += (size_t)E * 8;
    float* bufA     = (float*)p; p += (size_t)N * 64 * 4;
    float* bufB     = (float*)p; p += (size_t)N * 64 * 4;
    bf16*  xbf      = (bf16*)p;  p += (size_t)N * 64 * 2;   // layer-1 gather; reused as bfB
    bf16*  bfA      = (bf16*)p;  p += (size_t)N * 64 * 2;   // h1 bf16
    bf16*  bfB      = xbf;  // layer-2 output bf16 (x_bf dead after layer 1)

    dim3 blk(256);
    int nodeG = (N + 255) / 256;           // 196
    int edgeG = (E + 255) / 256;           // 3125
    int bigG  = (N * 64 + 255) / 256;      // 12500
    int NB = nodeG;

    init_k<<<bigG, blk, 0, stream>>>(packed, sums, cntG, x, xbf, N);
    hist_k<<<edgeG, blk, 0, stream>>>(P, col, packed, rank, E);
    blockscan_k<<<NB, blk, 0, stream>>>(packed, dis, scanTmp, partials, N);
    scanpartials_k<<<1, blk, 0, stream>>>(partials, NB);
    addback_k<<<nodeG, blk, 0, stream>>>(scanTmp, partials, packed, segStart, N, E);
    reorder_k<<<edgeG, blk, 0, stream>>>(row, col, P, dis, segStart, rank, sedge, E);
    fold_k<<<(64 * N_CLASSES + 255) / 256, blk, 0, stream>>>(W3, b3, Wl, bl, Wc, bc);

    int aggG = (N + 3) / 4;  // 1 node per wave, 4 waves/block

    // Layer 1: h1 = relu(agg(x) @ W1 + b1)   (self f32 from x, gather bf16 from xbf)
    agg_mm_k<1><<<aggG, blk, 0, stream>>>(x, xbf, sedge, segStart, dis, W1, b1, bufA, bfA, N);
    // Layer 2: h2 = relu(agg(h1) @ W2 + b2)
    agg_mm_k<1><<<aggG, blk, 0, stream>>>(bufA, bfA, sedge, segStart, dis, W2, b2, bufB, bfB, N);
    // Layer 3 (pure agg; W3/b3 folded into classifier)
    agg_mm_k<0><<<aggG, blk, 0, stream>>>(bufB, bfB, sedge, segStart, dis, nullptr, nullptr, bufA, nullptr, N);

    // pool + folded classifier
    int poolG = (N + 127) / 128;
    poolpart_k<<<poolG, blk, 0, stream>>>(bufA, batch, sums, cntG, N);
    classify_k<<<N_GRAPHS, dim3(64), 0, stream>>>(sums, cntG, Wc, bc, out);
}

// Round 11
// 295.945 us; speedup vs baseline: 1.7099x; 1.0915x over previous
//
#include <hip/hip_runtime.h>
#include <hip/hip_bf16.h>
#include <hip/hip_fp16.h>
#include <math.h>

#define N_GRAPHS 64
#define N_CLASSES 10
#define FIXSCALE 1048576.0f  // 2^20 fixed-point scale for packed degree sum

typedef __hip_bfloat16 bf16;

// edge record: row (16 high bits) | fp16 norm (16 low bits)
__device__ __forceinline__ unsigned int pack_edge(int r, float nv) {
    return ((unsigned int)r << 16) | (unsigned int)__half_as_ushort(__float2half(nv));
}

// ---------------- init: zero packed hist + pool buffers, convert x -> bf16 ----------------
__global__ void init_k(unsigned long long* __restrict__ packed,
                       float* __restrict__ sums, float* __restrict__ cntG,
                       const float* __restrict__ x, bf16* __restrict__ xbf, int n) {
    int i = blockIdx.x * 256 + threadIdx.x;
    if (i < n) packed[i] = 0ull;
    if (i < N_GRAPHS * 64) sums[i] = 0.0f;
    if (i < N_GRAPHS) cntG[i] = 0.0f;
    if (i < n * 64) xbf[i] = __float2bfloat16(x[i]);
}

// ---------------- one 64-bit atomic per edge: count<<40 | fix(sigmoid(P)) ----------------
// Returned old value's count field = this edge's rank within its destination
// segment -> stored coalesced, making the reorder pass atomic-free.
__global__ void hist_k(const float* __restrict__ P, const int* __restrict__ col,
                       unsigned long long* __restrict__ packed,
                       int* __restrict__ rank, int E) {
    int e = blockIdx.x * 256 + threadIdx.x;
    if (e < E) {
        float s = 1.0f / (1.0f + expf(-P[e]));
        unsigned long long v =
            (1ull << 40) | (unsigned long long)(s * FIXSCALE + 0.5f);
        unsigned long long old = atomicAdd(&packed[col[e]], v);
        rank[e] = (int)(old >> 40);
    }
}

// ---------------- scan stage 1 (+ fused dis = deg^-0.5) ----------------
__global__ __launch_bounds__(256) void blockscan_k(const unsigned long long* __restrict__ packed,
                                                   float* __restrict__ dis,
                                                   int* __restrict__ scanTmp,
                                                   int* __restrict__ partials, int n) {
    __shared__ int sd[256];
    int t = threadIdx.x;
    int i = blockIdx.x * 256 + t;
    int v = 0;
    if (i < n) {
        unsigned long long pk = packed[i];
        float deg = 1.0f + (float)(pk & ((1ull << 40) - 1)) * (1.0f / FIXSCALE);
        dis[i] = 1.0f / sqrtf(deg);
        v = (int)(pk >> 40);
    }
    sd[t] = v;
    __syncthreads();
    for (int o = 1; o < 256; o <<= 1) {
        int x = (t >= o) ? sd[t - o] : 0;
        __syncthreads();
        sd[t] += x;
        __syncthreads();
    }
    if (i < n) scanTmp[i] = sd[t];
    if (t == 255) partials[blockIdx.x] = sd[255];
}

// ---------------- scan stage 2: exclusive scan of block partials (NB <= 256) ----------------
__global__ __launch_bounds__(256) void scanpartials_k(int* __restrict__ partials, int nb) {
    __shared__ int sd[256];
    int t = threadIdx.x;
    int v = (t < nb) ? partials[t] : 0;
    sd[t] = v;
    __syncthreads();
    for (int o = 1; o < 256; o <<= 1) {
        int x = (t >= o) ? sd[t - o] : 0;
        __syncthreads();
        sd[t] += x;
        __syncthreads();
    }
    if (t < nb) partials[t] = sd[t] - v;  // exclusive
}

// ---------------- scan stage 3: segStart (exclusive) ----------------
__global__ void addback_k(const int* __restrict__ scanTmp, const int* __restrict__ partials,
                          const unsigned long long* __restrict__ packed,
                          int* __restrict__ segStart, int n, int E) {
    int i = blockIdx.x * 256 + threadIdx.x;
    if (i < n) {
        int cnt = (int)(packed[i] >> 40);
        segStart[i] = scanTmp[i] + partials[i >> 8] - cnt;
    }
    if (i == 0) segStart[n] = E;
}

// ---------------- reorder: atomic-free, pos = segStart[col] + rank; 4 B packed record ----------------
__global__ void reorder_k(const int* __restrict__ row, const int* __restrict__ col,
                          const float* __restrict__ P, const float* __restrict__ dis,
                          const int* __restrict__ segStart, const int* __restrict__ rank,
                          unsigned int* __restrict__ sedge, int E) {
    int e = blockIdx.x * 256 + threadIdx.x;
    if (e < E) {
        int r = row[e], c = col[e];
        float s = 1.0f / (1.0f + expf(-P[e]));
        float nv = dis[r] * s * dis[c];
        int pos = segStart[c] + rank[e];
        sedge[pos] = pack_edge(r, nv);
    }
}

// ---------------- fold tail linear ops: Wc = W3 @ Wl, bc = b3 @ Wl + bl ----------------
// needs 640 threads -> launched with 3 blocks of 256.
__global__ void fold_k(const float* __restrict__ W3, const float* __restrict__ b3,
                       const float* __restrict__ Wl, const float* __restrict__ bl,
                       float* __restrict__ Wc, float* __restrict__ bc) {
    int t = blockIdx.x * 256 + threadIdx.x;
    if (t < 64 * N_CLASSES) {
        int k = t / N_CLASSES, c = t % N_CLASSES;
        float acc = 0.0f;
        for (int m = 0; m < 64; ++m) acc += W3[k * 64 + m] * Wl[m * N_CLASSES + c];
        Wc[t] = acc;
    }
    if (t < N_CLASSES) {
        float acc = bl[t];
        for (int m = 0; m < 64; ++m) acc += b3[m] * Wl[m * N_CLASSES + t];
        bc[t] = acc;
    }
}

__device__ __forceinline__ float edge_term(unsigned int v, const bf16* hb, int lane) {
    int r = (int)(v >> 16);
    float nv = __half2float(__ushort_as_half((unsigned short)(v & 0xFFFFu)));
    return nv * __bfloat162float(hb[r * 64 + lane]);
}

// ---------------- fused layer: agg (f32 self + bf16 CSR gather) -> [@W + b -> relu] ----------------
// One node per wave; node wave-uniform (readfirstlane) so edge records are
// scalar loads (s_load_dwordx4 for 4 at a time). 4 accumulators keep 4 gathers
// in flight. MODE 1: W in LDS, readlane-GEMM epilogue + bf16 copy out.
// MODE 0: pure aggregation (tail folded into classifier).
template <int MODE>
__global__ __launch_bounds__(256) void agg_mm_k(const float* __restrict__ hf,
                                                const bf16* __restrict__ hb,
                                                const unsigned int* __restrict__ sedge,
                                                const int* __restrict__ segStart,
                                                const float* __restrict__ dis,
                                                const float* __restrict__ W,
                                                const float* __restrict__ b,
                                                float* __restrict__ out,
                                                bf16* __restrict__ out_bf, int n) {
    __shared__ float Wlds[MODE ? 64 * 64 : 1];
    int tid = threadIdx.x;
    if (MODE == 1) {
        for (int i = tid; i < 64 * 64; i += 256) Wlds[i] = W[i];
        __syncthreads();
    }
    int node = __builtin_amdgcn_readfirstlane(blockIdx.x * 4 + (tid >> 6));
    if (node >= n) return;
    int lane = tid & 63;

    float bv = (MODE == 1) ? b[lane] : 0.0f;
    float d = dis[node];
    float acc = d * d * hf[node * 64 + lane];  // self loop (weight 1), full f32
    int start = segStart[node];
    int end = segStart[node + 1];

    float a0 = 0.0f, a1 = 0.0f, a2 = 0.0f, a3 = 0.0f;
    int e = start;
    for (; e + 4 <= end; e += 4) {   // 4 uniform loads batch into s_load_dwordx4
        unsigned int v0 = sedge[e];
        unsigned int v1 = sedge[e + 1];
        unsigned int v2 = sedge[e + 2];
        unsigned int v3 = sedge[e + 3];
        a0 += edge_term(v0, hb, lane);
        a1 += edge_term(v1, hb, lane);
        a2 += edge_term(v2, hb, lane);
        a3 += edge_term(v3, hb, lane);
    }
    for (; e < end; ++e) a0 += edge_term(sedge[e], hb, lane);
    acc += (a0 + a1) + (a2 + a3);

    if (MODE == 1) {
        float o = bv;
#pragma unroll
        for (int k = 0; k < 64; ++k) {
            float wk = Wlds[k * 64 + lane];  // 2 lanes/bank: conflict-free
            float av = __int_as_float(
                __builtin_amdgcn_readlane(__float_as_int(acc), k));
            o = fmaf(av, wk, o);
        }
        o = fmaxf(o, 0.0f);
        out[node * 64 + lane] = o;
        out_bf[node * 64 + lane] = __float2bfloat16(o);
    } else {
        out[node * 64 + lane] = acc;
    }
}

// ---------------- pooling phase A: segmented partial sums, flush on graph change ----------------
__global__ __launch_bounds__(256) void poolpart_k(const float* __restrict__ h,
                                                  const int* __restrict__ batch,
                                                  float* __restrict__ sums,
                                                  float* __restrict__ cntG, int n) {
    int wave = threadIdx.x >> 6, lane = threadIdx.x & 63;
    int base = blockIdx.x * 128 + wave * 32;
    if (base >= n) return;
    int end = base + 32; if (end > n) end = n;
    int g = batch[base];
    float acc = 0.0f;
    int run = 0;
    for (int i = base; i < end; ++i) {
        int gi = batch[i];
        if (gi != g) {
            atomicAdd(&sums[g * 64 + lane], acc);
            if (lane == 0) atomicAdd(&cntG[g], (float)run);
            g = gi; acc = 0.0f; run = 0;
        }
        acc += h[i * 64 + lane];
        ++run;
    }
    atomicAdd(&sums[g * 64 + lane], acc);
    if (lane == 0) atomicAdd(&cntG[g], (float)run);
}

// ---------------- pooling phase B: mean + folded classifier (Wc, bc) ----------------
__global__ void classify_k(const float* __restrict__ sums, const float* __restrict__ cntG,
                           const float* __restrict__ Wc, const float* __restrict__ bc,
                           float* __restrict__ out) {
    __shared__ float pooled[64];
    int g = blockIdx.x;
    int t = threadIdx.x;  // 64
    float inv = 1.0f / fmaxf(cntG[g], 1.0f);
    pooled[t] = sums[g * 64 + t] * inv;
    __syncthreads();
    if (t < N_CLASSES) {
        float acc = bc[t];
        for (int k = 0; k < 64; ++k) acc += pooled[k] * Wc[k * N_CLASSES + t];
        out[g * N_CLASSES + t] = acc;
    }
}

extern "C" void kernel_launch(void* const* d_in, const int* in_sizes, int n_in,
                              void* d_out, int out_size, void* d_ws, size_t ws_size,
                              hipStream_t stream) {
    const float* x     = (const float*)d_in[0];
    const int*   eidx  = (const int*)d_in[1];
    const int*   batch = (const int*)d_in[2];
    const float* P     = (const float*)d_in[3];
    const float* W1 = (const float*)d_in[4];
    const float* b1 = (const float*)d_in[5];
    const float* W2 = (const float*)d_in[6];
    const float* b2 = (const float*)d_in[7];
    const float* W3 = (const float*)d_in[8];
    const float* b3 = (const float*)d_in[9];
    const float* Wl = (const float*)d_in[10];
    const float* bl = (const float*)d_in[11];
    float* out = (float*)d_out;

    const int N = in_sizes[2];      // 50000
    const int E = in_sizes[3];      // 800000
    const int* row = eidx;
    const int* col = eidx + E;

    // workspace layout
    char* p = (char*)d_ws;
    unsigned long long* packed = (unsigned long long*)p; p += (size_t)N * 8;
    float* dis      = (float*)p; p += (size_t)N * 4;
    int*   scanTmp  = (int*)p;   p += (size_t)N * 4;
    int*   segStart = (int*)p;   p += (size_t)(N + 1) * 4;
    int*   partials = (int*)p;   p += 256 * 4;
    float* sums     = (float*)p; p += (size_t)N_GRAPHS * 64 * 4;
    float* cntG     = (float*)p; p += (size_t)N_GRAPHS * 4;
    float* Wc       = (float*)p; p += (size_t)64 * N_CLASSES * 4;
    float* bc       = (float*)p; p += (size_t)N_CLASSES * 4;
    int*   rank     = (int*)p;   p += (size_t)E * 4;
    unsigned int* sedge = (unsigned int*)p; p += (size_t)E * 4;
    float* bufA     = (float*)p; p += (size_t)N * 64 * 4;
    float* bufB     = (float*)p; p += (size_t)N * 64 * 4;
    bf16*  xbf      = (bf16*)p;  p += (size_t)N * 64 * 2;   // layer-1 gather; reused as bfB
    bf16*  bfA      = (bf16*)p;  p += (size_t)N * 64 * 2;   // h1 bf16
    bf16*  bfB      = xbf;  // layer-2 output bf16 (x_bf dead after layer 1)

    dim3 blk(256);
    int nodeG = (N + 255) / 256;           // 196
    int edgeG = (E + 255) / 256;           // 3125
    int bigG  = (N * 64 + 255) / 256;      // 12500
    int NB = nodeG;

    init_k<<<bigG, blk, 0, stream>>>(packed, sums, cntG, x, xbf, N);
    hist_k<<<edgeG, blk, 0, stream>>>(P, col, packed, rank, E);
    blockscan_k<<<NB, blk, 0, stream>>>(packed, dis, scanTmp, partials, N);
    scanpartials_k<<<1, blk, 0, stream>>>(partials, NB);
    addback_k<<<nodeG, blk, 0, stream>>>(scanTmp, partials, packed, segStart, N, E);
    reorder_k<<<edgeG, blk, 0, stream>>>(row, col, P, dis, segStart, rank, sedge, E);
    fold_k<<<(64 * N_CLASSES + 255) / 256, blk, 0, stream>>>(W3, b3, Wl, bl, Wc, bc);

    int aggG = (N + 3) / 4;  // 1 node per wave, 4 waves/block

    // Layer 1: h1 = relu(agg(x) @ W1 + b1)   (self f32 from x, gather bf16 from xbf)
    agg_mm_k<1><<<aggG, blk, 0, stream>>>(x, xbf, sedge, segStart, dis, W1, b1, bufA, bfA, N);
    // Layer 2: h2 = relu(agg(h1) @ W2 + b2)
    agg_mm_k<1><<<aggG, blk, 0, stream>>>(bufA, bfA, sedge, segStart, dis, W2, b2, bufB, bfB, N);
    // Layer 3 (pure agg; W3/b3 folded into classifier)
    agg_mm_k<0><<<aggG, blk, 0, stream>>>(bufB, bfB, sedge, segStart, dis, nullptr, nullptr, bufA, nullptr, N);

    // pool + folded classifier
    int poolG = (N + 127) / 128;
    poolpart_k<<<poolG, blk, 0, stream>>>(bufA, batch, sums, cntG, N);
    classify_k<<<N_GRAPHS, dim3(64), 0, stream>>>(sums, cntG, Wc, bc, out);
}

// Round 12
// 292.130 us; speedup vs baseline: 1.7322x; 1.0131x over previous
//
#include <hip/hip_runtime.h>
#include <hip/hip_bf16.h>
#include <hip/hip_fp16.h>
#include <math.h>

#define N_GRAPHS 64
#define N_CLASSES 10
#define FIXSCALE 262144.0f  // 2^18 fixed-point scale for packed degree sum (24-bit field)

typedef __hip_bfloat16 bf16;

// edge record: row (16 high bits) | fp16 norm (16 low bits)
__device__ __forceinline__ unsigned int pack_edge(int r, float nv) {
    return ((unsigned int)r << 16) | (unsigned int)__half_as_ushort(__float2half(nv));
}

// ---------------- init: zero packed hist + pool buffers, convert x -> bf16 ----------------
__global__ void init_k(unsigned int* __restrict__ packed,
                       float* __restrict__ sums, float* __restrict__ cntG,
                       const float* __restrict__ x, bf16* __restrict__ xbf, int n) {
    int i = blockIdx.x * 256 + threadIdx.x;
    if (i < n) packed[i] = 0u;
    if (i < N_GRAPHS * 64) sums[i] = 0.0f;
    if (i < N_GRAPHS) cntG[i] = 0.0f;
    if (i < n * 64) xbf[i] = __float2bfloat16(x[i]);
}

// ---------------- one 32-bit atomic per edge: count<<24 | fix18(sigmoid(P)) ----------------
// deg is ~Poisson(16): count<64 and weight-sum<64.0 with overwhelming margin, so
// 8-bit count / 24-bit fixed-point weight cannot overflow in practice.
// Returned old value's count field = this edge's rank within its destination segment.
__global__ void hist_k(const float* __restrict__ P, const int* __restrict__ col,
                       unsigned int* __restrict__ packed,
                       int* __restrict__ rank, int E) {
    int e = blockIdx.x * 256 + threadIdx.x;
    if (e < E) {
        float s = 1.0f / (1.0f + expf(-P[e]));
        unsigned int v = (1u << 24) | (unsigned int)(s * FIXSCALE + 0.5f);
        unsigned int old = atomicAdd(&packed[col[e]], v);
        rank[e] = (int)(old >> 24);
    }
}

// ---------------- scan stage 1 (+ fused dis = deg^-0.5) ----------------
__global__ __launch_bounds__(256) void blockscan_k(const unsigned int* __restrict__ packed,
                                                   float* __restrict__ dis,
                                                   int* __restrict__ scanTmp,
                                                   int* __restrict__ partials, int n) {
    __shared__ int sd[256];
    int t = threadIdx.x;
    int i = blockIdx.x * 256 + t;
    int v = 0;
    if (i < n) {
        unsigned int pk = packed[i];
        float deg = 1.0f + (float)(pk & 0xFFFFFFu) * (1.0f / FIXSCALE);
        dis[i] = 1.0f / sqrtf(deg);
        v = (int)(pk >> 24);
    }
    sd[t] = v;
    __syncthreads();
    for (int o = 1; o < 256; o <<= 1) {
        int x = (t >= o) ? sd[t - o] : 0;
        __syncthreads();
        sd[t] += x;
        __syncthreads();
    }
    if (i < n) scanTmp[i] = sd[t];
    if (t == 255) partials[blockIdx.x] = sd[255];
}

// ---------------- scan stage 2: exclusive scan of block partials (NB <= 256) ----------------
__global__ __launch_bounds__(256) void scanpartials_k(int* __restrict__ partials, int nb) {
    __shared__ int sd[256];
    int t = threadIdx.x;
    int v = (t < nb) ? partials[t] : 0;
    sd[t] = v;
    __syncthreads();
    for (int o = 1; o < 256; o <<= 1) {
        int x = (t >= o) ? sd[t - o] : 0;
        __syncthreads();
        sd[t] += x;
        __syncthreads();
    }
    if (t < nb) partials[t] = sd[t] - v;  // exclusive
}

// ---------------- scan stage 3: segStart (exclusive) ----------------
__global__ void addback_k(const int* __restrict__ scanTmp, const int* __restrict__ partials,
                          const unsigned int* __restrict__ packed,
                          int* __restrict__ segStart, int n, int E) {
    int i = blockIdx.x * 256 + threadIdx.x;
    if (i < n) {
        int cnt = (int)(packed[i] >> 24);
        segStart[i] = scanTmp[i] + partials[i >> 8] - cnt;
    }
    if (i == 0) segStart[n] = E;
}

// ---------------- reorder: atomic-free, pos = segStart[col] + rank; 4 B packed record ----------------
__global__ void reorder_k(const int* __restrict__ row, const int* __restrict__ col,
                          const float* __restrict__ P, const float* __restrict__ dis,
                          const int* __restrict__ segStart, const int* __restrict__ rank,
                          unsigned int* __restrict__ sedge, int E) {
    int e = blockIdx.x * 256 + threadIdx.x;
    if (e < E) {
        int r = row[e], c = col[e];
        float s = 1.0f / (1.0f + expf(-P[e]));
        float nv = dis[r] * s * dis[c];
        int pos = segStart[c] + rank[e];
        sedge[pos] = pack_edge(r, nv);
    }
}

// ---------------- fold tail linear ops: Wc = W3 @ Wl, bc = b3 @ Wl + bl ----------------
// needs 640 threads -> launched with 3 blocks of 256.
__global__ void fold_k(const float* __restrict__ W3, const float* __restrict__ b3,
                       const float* __restrict__ Wl, const float* __restrict__ bl,
                       float* __restrict__ Wc, float* __restrict__ bc) {
    int t = blockIdx.x * 256 + threadIdx.x;
    if (t < 64 * N_CLASSES) {
        int k = t / N_CLASSES, c = t % N_CLASSES;
        float acc = 0.0f;
        for (int m = 0; m < 64; ++m) acc += W3[k * 64 + m] * Wl[m * N_CLASSES + c];
        Wc[t] = acc;
    }
    if (t < N_CLASSES) {
        float acc = bl[t];
        for (int m = 0; m < 64; ++m) acc += b3[m] * Wl[m * N_CLASSES + t];
        bc[t] = acc;
    }
}

__device__ __forceinline__ float edge_term(unsigned int v, const bf16* hb, int lane) {
    int r = (int)(v >> 16);
    float nv = __half2float(__ushort_as_half((unsigned short)(v & 0xFFFFu)));
    return nv * __bfloat162float(hb[r * 64 + lane]);
}

// ---------------- fused layer: agg (bf16 self + bf16 CSR gather) -> [@W + b -> relu] ----------------
// One node per wave; node wave-uniform (readfirstlane) so edge records come in
// as scalar loads (s_load_dwordx8 for 8 at a time); 8 gathers in flight.
// All h tensors stored bf16 only (no f32 round-trip). MODE 1: W in LDS,
// readlane-GEMM epilogue (4-way split FMA chains), bf16 out. MODE 0: pure
// aggregation (tail folded into classifier), f32 out for pooling.
template <int MODE>
__global__ __launch_bounds__(256) void agg_mm_k(const bf16* __restrict__ hb,
                                                const unsigned int* __restrict__ sedge,
                                                const int* __restrict__ segStart,
                                                const float* __restrict__ dis,
                                                const float* __restrict__ W,
                                                const float* __restrict__ b,
                                                float* __restrict__ out,
                                                bf16* __restrict__ out_bf, int n) {
    __shared__ float Wlds[MODE ? 64 * 64 : 1];
    int tid = threadIdx.x;
    if (MODE == 1) {
        for (int i = tid; i < 64 * 64; i += 256) Wlds[i] = W[i];
        __syncthreads();
    }
    int node = __builtin_amdgcn_readfirstlane(blockIdx.x * 4 + (tid >> 6));
    if (node >= n) return;
    int lane = tid & 63;

    float bv = (MODE == 1) ? b[lane] : 0.0f;
    float d = dis[node];
    float acc = d * d * __bfloat162float(hb[node * 64 + lane]);  // self loop (weight 1)
    int start = segStart[node];
    int end = segStart[node + 1];

    float a0 = 0.f, a1 = 0.f, a2 = 0.f, a3 = 0.f;
    float a4 = 0.f, a5 = 0.f, a6 = 0.f, a7 = 0.f;
    int e = start;
    for (; e + 8 <= end; e += 8) {   // uniform: batches into s_load_dwordx8
        unsigned int v0 = sedge[e];
        unsigned int v1 = sedge[e + 1];
        unsigned int v2 = sedge[e + 2];
        unsigned int v3 = sedge[e + 3];
        unsigned int v4 = sedge[e + 4];
        unsigned int v5 = sedge[e + 5];
        unsigned int v6 = sedge[e + 6];
        unsigned int v7 = sedge[e + 7];
        a0 += edge_term(v0, hb, lane);
        a1 += edge_term(v1, hb, lane);
        a2 += edge_term(v2, hb, lane);
        a3 += edge_term(v3, hb, lane);
        a4 += edge_term(v4, hb, lane);
        a5 += edge_term(v5, hb, lane);
        a6 += edge_term(v6, hb, lane);
        a7 += edge_term(v7, hb, lane);
    }
    for (; e < end; ++e) a0 += edge_term(sedge[e], hb, lane);
    acc += ((a0 + a1) + (a2 + a3)) + ((a4 + a5) + (a6 + a7));

    if (MODE == 1) {
        float o0 = bv, o1 = 0.f, o2 = 0.f, o3 = 0.f;  // 4-way split FMA chain
#pragma unroll
        for (int k = 0; k < 64; k += 4) {
            float av0 = __int_as_float(__builtin_amdgcn_readlane(__float_as_int(acc), k));
            float av1 = __int_as_float(__builtin_amdgcn_readlane(__float_as_int(acc), k + 1));
            float av2 = __int_as_float(__builtin_amdgcn_readlane(__float_as_int(acc), k + 2));
            float av3 = __int_as_float(__builtin_amdgcn_readlane(__float_as_int(acc), k + 3));
            o0 = fmaf(av0, Wlds[(k + 0) * 64 + lane], o0);
            o1 = fmaf(av1, Wlds[(k + 1) * 64 + lane], o1);
            o2 = fmaf(av2, Wlds[(k + 2) * 64 + lane], o2);
            o3 = fmaf(av3, Wlds[(k + 3) * 64 + lane], o3);
        }
        float o = fmaxf((o0 + o1) + (o2 + o3), 0.0f);
        out_bf[node * 64 + lane] = __float2bfloat16(o);
    } else {
        out[node * 64 + lane] = acc;
    }
}

// ---------------- pooling phase A: segmented partial sums, flush on graph change ----------------
__global__ __launch_bounds__(256) void poolpart_k(const float* __restrict__ h,
                                                  const int* __restrict__ batch,
                                                  float* __restrict__ sums,
                                                  float* __restrict__ cntG, int n) {
    int wave = threadIdx.x >> 6, lane = threadIdx.x & 63;
    int base = blockIdx.x * 128 + wave * 32;
    if (base >= n) return;
    int end = base + 32; if (end > n) end = n;
    int g = batch[base];
    float acc = 0.0f;
    int run = 0;
    for (int i = base; i < end; ++i) {
        int gi = batch[i];
        if (gi != g) {
            atomicAdd(&sums[g * 64 + lane], acc);
            if (lane == 0) atomicAdd(&cntG[g], (float)run);
            g = gi; acc = 0.0f; run = 0;
        }
        acc += h[i * 64 + lane];
        ++run;
    }
    atomicAdd(&sums[g * 64 + lane], acc);
    if (lane == 0) atomicAdd(&cntG[g], (float)run);
}

// ---------------- pooling phase B: mean + folded classifier (Wc, bc) ----------------
__global__ void classify_k(const float* __restrict__ sums, const float* __restrict__ cntG,
                           const float* __restrict__ Wc, const float* __restrict__ bc,
                           float* __restrict__ out) {
    __shared__ float pooled[64];
    int g = blockIdx.x;
    int t = threadIdx.x;  // 64
    float inv = 1.0f / fmaxf(cntG[g], 1.0f);
    pooled[t] = sums[g * 64 + t] * inv;
    __syncthreads();
    if (t < N_CLASSES) {
        float acc = bc[t];
        for (int k = 0; k < 64; ++k) acc += pooled[k] * Wc[k * N_CLASSES + t];
        out[g * N_CLASSES + t] = acc;
    }
}

extern "C" void kernel_launch(void* const* d_in, const int* in_sizes, int n_in,
                              void* d_out, int out_size, void* d_ws, size_t ws_size,
                              hipStream_t stream) {
    const float* x     = (const float*)d_in[0];
    const int*   eidx  = (const int*)d_in[1];
    const int*   batch = (const int*)d_in[2];
    const float* P     = (const float*)d_in[3];
    const float* W1 = (const float*)d_in[4];
    const float* b1 = (const float*)d_in[5];
    const float* W2 = (const float*)d_in[6];
    const float* b2 = (const float*)d_in[7];
    const float* W3 = (const float*)d_in[8];
    const float* b3 = (const float*)d_in[9];
    const float* Wl = (const float*)d_in[10];
    const float* bl = (const float*)d_in[11];
    float* out = (float*)d_out;

    const int N = in_sizes[2];      // 50000
    const int E = in_sizes[3];      // 800000
    const int* row = eidx;
    const int* col = eidx + E;

    // workspace layout
    char* p = (char*)d_ws;
    unsigned int* packed = (unsigned int*)p; p += (size_t)N * 4;
    float* dis      = (float*)p; p += (size_t)N * 4;
    int*   scanTmp  = (int*)p;   p += (size_t)N * 4;
    int*   segStart = (int*)p;   p += (size_t)(N + 1) * 4;
    int*   partials = (int*)p;   p += 256 * 4;
    float* sums     = (float*)p; p += (size_t)N_GRAPHS * 64 * 4;
    float* cntG     = (float*)p; p += (size_t)N_GRAPHS * 4;
    float* Wc       = (float*)p; p += (size_t)64 * N_CLASSES * 4;
    float* bc       = (float*)p; p += (size_t)N_CLASSES * 4;
    int*   rank     = (int*)p;   p += (size_t)E * 4;
    unsigned int* sedge = (unsigned int*)p; p += (size_t)E * 4;
    float* bufF     = (float*)p; p += (size_t)N * 64 * 4;   // f32 h3 for pooling
    bf16*  xbf      = (bf16*)p;  p += (size_t)N * 64 * 2;   // x bf16; reused as h2
    bf16*  bfA      = (bf16*)p;  p += (size_t)N * 64 * 2;   // h1 bf16
    bf16*  bfB      = xbf;  // h2 aliases xbf (x dead after layer 1)

    dim3 blk(256);
    int nodeG = (N + 255) / 256;           // 196
    int edgeG = (E + 255) / 256;           // 3125
    int bigG  = (N * 64 + 255) / 256;      // 12500
    int NB = nodeG;

    init_k<<<bigG, blk, 0, stream>>>(packed, sums, cntG, x, xbf, N);
    hist_k<<<edgeG, blk, 0, stream>>>(P, col, packed, rank, E);
    blockscan_k<<<NB, blk, 0, stream>>>(packed, dis, scanTmp, partials, N);
    scanpartials_k<<<1, blk, 0, stream>>>(partials, NB);
    addback_k<<<nodeG, blk, 0, stream>>>(scanTmp, partials, packed, segStart, N, E);
    reorder_k<<<edgeG, blk, 0, stream>>>(row, col, P, dis, segStart, rank, sedge, E);
    fold_k<<<(64 * N_CLASSES + 255) / 256, blk, 0, stream>>>(W3, b3, Wl, bl, Wc, bc);

    int aggG = (N + 3) / 4;  // 1 node per wave, 4 waves/block

    // Layer 1: h1 = relu(agg(x) @ W1 + b1)
    agg_mm_k<1><<<aggG, blk, 0, stream>>>(xbf, sedge, segStart, dis, W1, b1, nullptr, bfA, N);
    // Layer 2: h2 = relu(agg(h1) @ W2 + b2)
    agg_mm_k<1><<<aggG, blk, 0, stream>>>(bfA, sedge, segStart, dis, W2, b2, nullptr, bfB, N);
    // Layer 3 (pure agg; W3/b3 folded into classifier), f32 out for pooling
    agg_mm_k<0><<<aggG, blk, 0, stream>>>(bfB, sedge, segStart, dis, nullptr, nullptr, bufF, nullptr, N);

    // pool + folded classifier
    int poolG = (N + 127) / 128;
    poolpart_k<<<poolG, blk, 0, stream>>>(bufF, batch, sums, cntG, N);
    classify_k<<<N_GRAPHS, dim3(64), 0, stream>>>(sums, cntG, Wc, bc, out);
}

// Round 13
// 262.233 us; speedup vs baseline: 1.9297x; 1.1140x over previous
//
#include <hip/hip_runtime.h>
#include <hip/hip_bf16.h>
#include <hip/hip_fp16.h>
#include <math.h>

#define N_GRAPHS 64
#define N_CLASSES 10
#define FIXSCALE 262144.0f  // 2^18 fixed-point scale for packed degree sum (24-bit field)
#define MAXDEG 64           // deg ~ Poisson(16): P(deg>=64) ~ 1e-18/node — safe

typedef __hip_bfloat16 bf16;

// edge record: row (16 high bits) | fp16 sigmoid(P) (16 low bits). Zero record == no-op.
__device__ __forceinline__ unsigned int pack_edge(int r, float s) {
    return ((unsigned int)r << 16) | (unsigned int)__half_as_ushort(__float2half(s));
}

// ---------------- init: zero packed hist + pool buffers + ELL table ----------------
__global__ void init_k(unsigned int* __restrict__ packed,
                       float* __restrict__ sums, float* __restrict__ cntG,
                       unsigned int* __restrict__ ell, int n) {
    int i = blockIdx.x * 256 + threadIdx.x;
    if (i < n) packed[i] = 0u;
    if (i < N_GRAPHS * 64) sums[i] = 0.0f;
    if (i < N_GRAPHS) cntG[i] = 0.0f;
    if (i < n * MAXDEG) ell[i] = 0u;  // zero-pad: row 0, s = 0 -> contributes 0
}

// ---------------- hist + direct ELL scatter ----------------
// One u32 atomic per edge: count<<24 | fix18(sigmoid). Returned old count = this
// edge's rank in its destination segment -> write the edge record straight into
// ell[col*MAXDEG + rank]. No reorder pass, no scan, no rank array.
__global__ void hist_k(const float* __restrict__ P, const int* __restrict__ row,
                       const int* __restrict__ col,
                       unsigned int* __restrict__ packed,
                       unsigned int* __restrict__ ell, int E) {
    int e = blockIdx.x * 256 + threadIdx.x;
    if (e < E) {
        float s = 1.0f / (1.0f + expf(-P[e]));
        unsigned int v = (1u << 24) | (unsigned int)(s * FIXSCALE + 0.5f);
        unsigned int old = atomicAdd(&packed[col[e]], v);
        unsigned int rank = old >> 24;
        if (rank < MAXDEG) ell[col[e] * MAXDEG + rank] = pack_edge(row[e], s);
    }
}

// ---------------- dis = (1+sumw)^-0.5 and xg = bf16(dis * x) in one pass ----------------
__global__ void disxg_k(const unsigned int* __restrict__ packed,
                        const float* __restrict__ x,
                        float* __restrict__ dis, bf16* __restrict__ xg, int n) {
    int i = blockIdx.x * 256 + threadIdx.x;
    if (i < n * 64) {
        int node = i >> 6;
        unsigned int pk = packed[node];  // same word across the wave's node group: cache-hot
        float deg = 1.0f + (float)(pk & 0xFFFFFFu) * (1.0f / FIXSCALE);
        float dv = 1.0f / sqrtf(deg);
        xg[i] = __float2bfloat16(x[i] * dv);
        if ((i & 63) == 0) dis[node] = dv;
    }
}

// ---------------- fold tail linear ops: Wc = W3 @ Wl, bc = b3 @ Wl + bl ----------------
// needs 640 threads -> launched with 3 blocks of 256.
__global__ void fold_k(const float* __restrict__ W3, const float* __restrict__ b3,
                       const float* __restrict__ Wl, const float* __restrict__ bl,
                       float* __restrict__ Wc, float* __restrict__ bc) {
    int t = blockIdx.x * 256 + threadIdx.x;
    if (t < 64 * N_CLASSES) {
        int k = t / N_CLASSES, c = t % N_CLASSES;
        float acc = 0.0f;
        for (int m = 0; m < 64; ++m) acc += W3[k * 64 + m] * Wl[m * N_CLASSES + c];
        Wc[t] = acc;
    }
    if (t < N_CLASSES) {
        float acc = bl[t];
        for (int m = 0; m < 64; ++m) acc += b3[m] * Wl[m * N_CLASSES + t];
        bc[t] = acc;
    }
}

__device__ __forceinline__ float edge_term(unsigned int v, const bf16* g, int lane) {
    int r = (int)(v >> 16);
    float s = __half2float(__ushort_as_half((unsigned short)(v & 0xFFFFu)));
    return s * __bfloat162float(g[r * 64 + lane]);
}

// ---------------- fused layer on the dis-scaled table g = dis*h ----------------
// acc = dis_c * (g[node] + sum_e s_e * g[row_e])  (== reference agg exactly)
// One node per wave, wave-uniform node: ELL row (<= 64 recs, zero-padded to
// multiples of 8) streams in as scalar s_load_dwordx8; 8 gathers in flight.
// MODE 1: W in LDS, readlane-GEMM epilogue, writes g_next = dis*relu(W*acc+b).
// MODE 0: pure aggregation, f32 out for pooling (tail folded into classifier).
template <int MODE>
__global__ __launch_bounds__(256) void agg_mm_k(const bf16* __restrict__ g,
                                                const unsigned int* __restrict__ ell,
                                                const unsigned int* __restrict__ packed,
                                                const float* __restrict__ dis,
                                                const float* __restrict__ W,
                                                const float* __restrict__ b,
                                                float* __restrict__ out,
                                                bf16* __restrict__ out_bf, int n) {
    __shared__ float Wlds[MODE ? 64 * 64 : 1];
    int tid = threadIdx.x;
    if (MODE == 1) {
        for (int i = tid; i < 64 * 64; i += 256) Wlds[i] = W[i];
        __syncthreads();
    }
    int node = __builtin_amdgcn_readfirstlane(blockIdx.x * 4 + (tid >> 6));
    if (node >= n) return;
    int lane = tid & 63;

    float bv = (MODE == 1) ? b[lane] : 0.0f;
    float d = dis[node];
    int cnt = (int)(packed[node] >> 24);
    if (cnt > MAXDEG) cnt = MAXDEG;
    float acc = __bfloat162float(g[node * 64 + lane]);  // self loop: dis*h[node]
    const unsigned int* rowp = ell + node * MAXDEG;

    float a0 = 0.f, a1 = 0.f, a2 = 0.f, a3 = 0.f;
    float a4 = 0.f, a5 = 0.f, a6 = 0.f, a7 = 0.f;
    for (int j = 0; j < cnt; j += 8) {  // padded: j+7 < MAXDEG always; zero recs no-op
        unsigned int v0 = rowp[j];
        unsigned int v1 = rowp[j + 1];
        unsigned int v2 = rowp[j + 2];
        unsigned int v3 = rowp[j + 3];
        unsigned int v4 = rowp[j + 4];
        unsigned int v5 = rowp[j + 5];
        unsigned int v6 = rowp[j + 6];
        unsigned int v7 = rowp[j + 7];
        a0 += edge_term(v0, g, lane);
        a1 += edge_term(v1, g, lane);
        a2 += edge_term(v2, g, lane);
        a3 += edge_term(v3, g, lane);
        a4 += edge_term(v4, g, lane);
        a5 += edge_term(v5, g, lane);
        a6 += edge_term(v6, g, lane);
        a7 += edge_term(v7, g, lane);
    }
    acc += ((a0 + a1) + (a2 + a3)) + ((a4 + a5) + (a6 + a7));
    acc *= d;  // apply dis_c once

    if (MODE == 1) {
        float o0 = bv, o1 = 0.f, o2 = 0.f, o3 = 0.f;  // 4-way split FMA chain
#pragma unroll
        for (int k = 0; k < 64; k += 4) {
            float av0 = __int_as_float(__builtin_amdgcn_readlane(__float_as_int(acc), k));
            float av1 = __int_as_float(__builtin_amdgcn_readlane(__float_as_int(acc), k + 1));
            float av2 = __int_as_float(__builtin_amdgcn_readlane(__float_as_int(acc), k + 2));
            float av3 = __int_as_float(__builtin_amdgcn_readlane(__float_as_int(acc), k + 3));
            o0 = fmaf(av0, Wlds[(k + 0) * 64 + lane], o0);
            o1 = fmaf(av1, Wlds[(k + 1) * 64 + lane], o1);
            o2 = fmaf(av2, Wlds[(k + 2) * 64 + lane], o2);
            o3 = fmaf(av3, Wlds[(k + 3) * 64 + lane], o3);
        }
        float o = fmaxf((o0 + o1) + (o2 + o3), 0.0f);
        out_bf[node * 64 + lane] = __float2bfloat16(d * o);  // store g_next = dis*h_next
    } else {
        out[node * 64 + lane] = acc;
    }
}

// ---------------- pooling phase A: segmented partial sums, flush on graph change ----------------
__global__ __launch_bounds__(256) void poolpart_k(const float* __restrict__ h,
                                                  const int* __restrict__ batch,
                                                  float* __restrict__ sums,
                                                  float* __restrict__ cntG, int n) {
    int wave = threadIdx.x >> 6, lane = threadIdx.x & 63;
    int base = blockIdx.x * 128 + wave * 32;
    if (base >= n) return;
    int end = base + 32; if (end > n) end = n;
    int g = batch[base];
    float acc = 0.0f;
    int run = 0;
    for (int i = base; i < end; ++i) {
        int gi = batch[i];
        if (gi != g) {
            atomicAdd(&sums[g * 64 + lane], acc);
            if (lane == 0) atomicAdd(&cntG[g], (float)run);
            g = gi; acc = 0.0f; run = 0;
        }
        acc += h[i * 64 + lane];
        ++run;
    }
    atomicAdd(&sums[g * 64 + lane], acc);
    if (lane == 0) atomicAdd(&cntG[g], (float)run);
}

// ---------------- pooling phase B: mean + folded classifier (Wc, bc) ----------------
__global__ void classify_k(const float* __restrict__ sums, const float* __restrict__ cntG,
                           const float* __restrict__ Wc, const float* __restrict__ bc,
                           float* __restrict__ out) {
    __shared__ float pooled[64];
    int g = blockIdx.x;
    int t = threadIdx.x;  // 64
    float inv = 1.0f / fmaxf(cntG[g], 1.0f);
    pooled[t] = sums[g * 64 + t] * inv;
    __syncthreads();
    if (t < N_CLASSES) {
        float acc = bc[t];
        for (int k = 0; k < 64; ++k) acc += pooled[k] * Wc[k * N_CLASSES + t];
        out[g * N_CLASSES + t] = acc;
    }
}

extern "C" void kernel_launch(void* const* d_in, const int* in_sizes, int n_in,
                              void* d_out, int out_size, void* d_ws, size_t ws_size,
                              hipStream_t stream) {
    const float* x     = (const float*)d_in[0];
    const int*   eidx  = (const int*)d_in[1];
    const int*   batch = (const int*)d_in[2];
    const float* P     = (const float*)d_in[3];
    const float* W1 = (const float*)d_in[4];
    const float* b1 = (const float*)d_in[5];
    const float* W2 = (const float*)d_in[6];
    const float* b2 = (const float*)d_in[7];
    const float* W3 = (const float*)d_in[8];
    const float* b3 = (const float*)d_in[9];
    const float* Wl = (const float*)d_in[10];
    const float* bl = (const float*)d_in[11];
    float* out = (float*)d_out;

    const int N = in_sizes[2];      // 50000
    const int E = in_sizes[3];      // 800000
    const int* row = eidx;
    const int* col = eidx + E;

    // workspace layout
    char* p = (char*)d_ws;
    unsigned int* packed = (unsigned int*)p; p += (size_t)N * 4;
    float* dis      = (float*)p; p += (size_t)N * 4;
    float* sums     = (float*)p; p += (size_t)N_GRAPHS * 64 * 4;
    float* cntG     = (float*)p; p += (size_t)N_GRAPHS * 4;
    float* Wc       = (float*)p; p += (size_t)64 * N_CLASSES * 4;
    float* bc       = (float*)p; p += (size_t)N_CLASSES * 4;
    unsigned int* ell = (unsigned int*)p; p += (size_t)N * MAXDEG * 4;  // 12.8 MB
    float* bufF     = (float*)p; p += (size_t)N * 64 * 4;   // f32 h3 for pooling
    bf16*  xg       = (bf16*)p;  p += (size_t)N * 64 * 2;   // g0 = dis*x; reused as g2
    bf16*  gA       = (bf16*)p;  p += (size_t)N * 64 * 2;   // g1
    bf16*  gB       = xg;  // g2 aliases xg (g0 dead after layer 1)

    dim3 blk(256);
    int edgeG = (E + 255) / 256;           // 3125
    int bigG  = (N * 64 + 255) / 256;      // 12500

    init_k<<<bigG, blk, 0, stream>>>(packed, sums, cntG, ell, N);
    hist_k<<<edgeG, blk, 0, stream>>>(P, row, col, packed, ell, E);
    disxg_k<<<bigG, blk, 0, stream>>>(packed, x, dis, xg, N);
    fold_k<<<(64 * N_CLASSES + 255) / 256, blk, 0, stream>>>(W3, b3, Wl, bl, Wc, bc);

    int aggG = (N + 3) / 4;  // 1 node per wave, 4 waves/block

    // Layer 1: g1 = dis*relu(agg(x) @ W1 + b1)
    agg_mm_k<1><<<aggG, blk, 0, stream>>>(xg, ell, packed, dis, W1, b1, nullptr, gA, N);
    // Layer 2: g2 = dis*relu(agg(h1) @ W2 + b2)
    agg_mm_k<1><<<aggG, blk, 0, stream>>>(gA, ell, packed, dis, W2, b2, nullptr, gB, N);
    // Layer 3 (pure agg; W3/b3 folded into classifier), f32 out for pooling
    agg_mm_k<0><<<aggG, blk, 0, stream>>>(gB, ell, packed, dis, nullptr, nullptr, bufF, nullptr, N);

    // pool + folded classifier
    int poolG = (N + 127) / 128;
    poolpart_k<<<poolG, blk, 0, stream>>>(bufF, batch, sums, cntG, N);
    classify_k<<<N_GRAPHS, dim3(64), 0, stream>>>(sums, cntG, Wc, bc, out);
}

// Round 14
// 257.971 us; speedup vs baseline: 1.9616x; 1.0165x over previous
//
#include <hip/hip_runtime.h>
#include <hip/hip_bf16.h>
#include <hip/hip_fp16.h>
#include <math.h>

#define N_GRAPHS 64
#define N_CLASSES 10
#define FIXSCALE 262144.0f  // 2^18 fixed-point scale for packed degree sum (24-bit field)
#define MAXDEG 64           // deg ~ Poisson(16): P(deg>=64) ~ 1e-18/node — safe

typedef __hip_bfloat16 bf16;

// edge record: row (16 high bits) | fp16 sigmoid(P) (16 low bits). Zero record == no-op.
__device__ __forceinline__ unsigned int pack_edge(int r, float s) {
    return ((unsigned int)r << 16) | (unsigned int)__half_as_ushort(__float2half(s));
}

// ---------------- init: zero packed hist + pool buffers (NO ELL zeroing) ----------------
__global__ void init_k(unsigned int* __restrict__ packed,
                       float* __restrict__ sums, float* __restrict__ cntG, int n) {
    int i = blockIdx.x * 256 + threadIdx.x;
    if (i < n) packed[i] = 0u;
    if (i < N_GRAPHS * 64) sums[i] = 0.0f;
    if (i < N_GRAPHS) cntG[i] = 0.0f;
}

// ---------------- hist + direct ELL scatter ----------------
// One u32 atomic per edge: count<<24 | fix18(sigmoid). Returned old count = this
// edge's rank in its destination segment -> write the edge record straight into
// ell[col*MAXDEG + rank]. No reorder pass, no scan, no rank array.
__global__ void hist_k(const float* __restrict__ P, const int* __restrict__ row,
                       const int* __restrict__ col,
                       unsigned int* __restrict__ packed,
                       unsigned int* __restrict__ ell, int E) {
    int e = blockIdx.x * 256 + threadIdx.x;
    if (e < E) {
        float s = 1.0f / (1.0f + expf(-P[e]));
        unsigned int v = (1u << 24) | (unsigned int)(s * FIXSCALE + 0.5f);
        unsigned int old = atomicAdd(&packed[col[e]], v);
        unsigned int rank = old >> 24;
        if (rank < MAXDEG) ell[col[e] * MAXDEG + rank] = pack_edge(row[e], s);
    }
}

// ---------------- dis, xg = bf16(dis*x), and ELL tail zero-pad in one pass ----------------
// Zero-pads only slots [cnt, roundup16(cnt)) (<=15 per node) so the agg loop can
// run branch-free 16-wide batches — replaces zeroing the whole 12.8 MB table.
__global__ void disxg_k(const unsigned int* __restrict__ packed,
                        const float* __restrict__ x,
                        float* __restrict__ dis, bf16* __restrict__ xg,
                        unsigned int* __restrict__ ell, int n) {
    int i = blockIdx.x * 256 + threadIdx.x;
    if (i < n * 64) {
        int node = i >> 6;
        int lane = i & 63;
        unsigned int pk = packed[node];  // same word across the node's 64 lanes: cache-hot
        float deg = 1.0f + (float)(pk & 0xFFFFFFu) * (1.0f / FIXSCALE);
        float dv = 1.0f / sqrtf(deg);
        xg[i] = __float2bfloat16(x[i] * dv);
        if (lane == 0) dis[node] = dv;
        int cnt = (int)(pk >> 24);
        if (cnt > MAXDEG) cnt = MAXDEG;
        int pad = ((cnt + 15) & ~15) - cnt;  // 0..15
        if (lane < pad) ell[node * MAXDEG + cnt + lane] = 0u;
    }
}

// ---------------- fold tail linear ops: Wc = W3 @ Wl, bc = b3 @ Wl + bl ----------------
// needs 640 threads -> launched with 3 blocks of 256.
__global__ void fold_k(const float* __restrict__ W3, const float* __restrict__ b3,
                       const float* __restrict__ Wl, const float* __restrict__ bl,
                       float* __restrict__ Wc, float* __restrict__ bc) {
    int t = blockIdx.x * 256 + threadIdx.x;
    if (t < 64 * N_CLASSES) {
        int k = t / N_CLASSES, c = t % N_CLASSES;
        float acc = 0.0f;
        for (int m = 0; m < 64; ++m) acc += W3[k * 64 + m] * Wl[m * N_CLASSES + c];
        Wc[t] = acc;
    }
    if (t < N_CLASSES) {
        float acc = bl[t];
        for (int m = 0; m < 64; ++m) acc += b3[m] * Wl[m * N_CLASSES + t];
        bc[t] = acc;
    }
}

__device__ __forceinline__ float edge_term(unsigned int v, const bf16* g, int lane) {
    int r = (int)(v >> 16);
    float s = __half2float(__ushort_as_half((unsigned short)(v & 0xFFFFu)));
    return s * __bfloat162float(g[r * 64 + lane]);
}

// ---------------- fused layer on the dis-scaled table g = dis*h ----------------
// acc = dis_c * (g[node] + sum_e s_e * g[row_e])  (== reference agg exactly)
// One node per wave, wave-uniform node: ELL row streams in as scalar
// s_load_dwordx8 pairs; 16 gathers in flight (zero-padded to multiples of 16,
// zero record contributes exactly 0). MODE 1: W in LDS, readlane-GEMM epilogue,
// writes g_next = dis*relu(W*acc+b). MODE 0: pure agg, f32 out for pooling.
template <int MODE>
__global__ __launch_bounds__(256) void agg_mm_k(const bf16* __restrict__ g,
                                                const unsigned int* __restrict__ ell,
                                                const unsigned int* __restrict__ packed,
                                                const float* __restrict__ dis,
                                                const float* __restrict__ W,
                                                const float* __restrict__ b,
                                                float* __restrict__ out,
                                                bf16* __restrict__ out_bf, int n) {
    __shared__ float Wlds[MODE ? 64 * 64 : 1];
    int tid = threadIdx.x;
    if (MODE == 1) {
        for (int i = tid; i < 64 * 64; i += 256) Wlds[i] = W[i];
        __syncthreads();
    }
    int node = __builtin_amdgcn_readfirstlane(blockIdx.x * 4 + (tid >> 6));
    if (node >= n) return;
    int lane = tid & 63;

    float bv = (MODE == 1) ? b[lane] : 0.0f;
    float d = dis[node];
    int cnt = (int)(packed[node] >> 24);
    if (cnt > MAXDEG) cnt = MAXDEG;
    int cnt16 = (cnt + 15) & ~15;  // tail slots zeroed by disxg_k
    float acc = __bfloat162float(g[node * 64 + lane]);  // self loop: dis*h[node]
    const unsigned int* rowp = ell + node * MAXDEG;

    float a[16];
#pragma unroll
    for (int t = 0; t < 16; ++t) a[t] = 0.0f;
    for (int j = 0; j < cnt16; j += 16) {  // uniform: 2x s_load_dwordx8
        unsigned int v[16];
#pragma unroll
        for (int t = 0; t < 16; ++t) v[t] = rowp[j + t];
#pragma unroll
        for (int t = 0; t < 16; ++t) a[t] += edge_term(v[t], g, lane);
    }
#pragma unroll
    for (int off = 8; off >= 1; off >>= 1)
#pragma unroll
        for (int t = 0; t < off; ++t) a[t] += a[t + off];
    acc += a[0];
    acc *= d;  // apply dis_c once

    if (MODE == 1) {
        float o0 = bv, o1 = 0.f, o2 = 0.f, o3 = 0.f;  // 4-way split FMA chain
#pragma unroll
        for (int k = 0; k < 64; k += 4) {
            float av0 = __int_as_float(__builtin_amdgcn_readlane(__float_as_int(acc), k));
            float av1 = __int_as_float(__builtin_amdgcn_readlane(__float_as_int(acc), k + 1));
            float av2 = __int_as_float(__builtin_amdgcn_readlane(__float_as_int(acc), k + 2));
            float av3 = __int_as_float(__builtin_amdgcn_readlane(__float_as_int(acc), k + 3));
            o0 = fmaf(av0, Wlds[(k + 0) * 64 + lane], o0);
            o1 = fmaf(av1, Wlds[(k + 1) * 64 + lane], o1);
            o2 = fmaf(av2, Wlds[(k + 2) * 64 + lane], o2);
            o3 = fmaf(av3, Wlds[(k + 3) * 64 + lane], o3);
        }
        float o = fmaxf((o0 + o1) + (o2 + o3), 0.0f);
        out_bf[node * 64 + lane] = __float2bfloat16(d * o);  // store g_next = dis*h_next
    } else {
        out[node * 64 + lane] = acc;
    }
}

// ---------------- pooling phase A: segmented partial sums, flush on graph change ----------------
__global__ __launch_bounds__(256) void poolpart_k(const float* __restrict__ h,
                                                  const int* __restrict__ batch,
                                                  float* __restrict__ sums,
                                                  float* __restrict__ cntG, int n) {
    int wave = threadIdx.x >> 6, lane = threadIdx.x & 63;
    int base = blockIdx.x * 128 + wave * 32;
    if (base >= n) return;
    int end = base + 32; if (end > n) end = n;
    int g = batch[base];
    float acc = 0.0f;
    int run = 0;
    for (int i = base; i < end; ++i) {
        int gi = batch[i];
        if (gi != g) {
            atomicAdd(&sums[g * 64 + lane], acc);
            if (lane == 0) atomicAdd(&cntG[g], (float)run);
            g = gi; acc = 0.0f; run = 0;
        }
        acc += h[i * 64 + lane];
        ++run;
    }
    atomicAdd(&sums[g * 64 + lane], acc);
    if (lane == 0) atomicAdd(&cntG[g], (float)run);
}

// ---------------- pooling phase B: mean + folded classifier (Wc, bc) ----------------
__global__ void classify_k(const float* __restrict__ sums, const float* __restrict__ cntG,
                           const float* __restrict__ Wc, const float* __restrict__ bc,
                           float* __restrict__ out) {
    __shared__ float pooled[64];
    int g = blockIdx.x;
    int t = threadIdx.x;  // 64
    float inv = 1.0f / fmaxf(cntG[g], 1.0f);
    pooled[t] = sums[g * 64 + t] * inv;
    __syncthreads();
    if (t < N_CLASSES) {
        float acc = bc[t];
        for (int k = 0; k < 64; ++k) acc += pooled[k] * Wc[k * N_CLASSES + t];
        out[g * N_CLASSES + t] = acc;
    }
}

extern "C" void kernel_launch(void* const* d_in, const int* in_sizes, int n_in,
                              void* d_out, int out_size, void* d_ws, size_t ws_size,
                              hipStream_t stream) {
    const float* x     = (const float*)d_in[0];
    const int*   eidx  = (const int*)d_in[1];
    const int*   batch = (const int*)d_in[2];
    const float* P     = (const float*)d_in[3];
    const float* W1 = (const float*)d_in[4];
    const float* b1 = (const float*)d_in[5];
    const float* W2 = (const float*)d_in[6];
    const float* b2 = (const float*)d_in[7];
    const float* W3 = (const float*)d_in[8];
    const float* b3 = (const float*)d_in[9];
    const float* Wl = (const float*)d_in[10];
    const float* bl = (const float*)d_in[11];
    float* out = (float*)d_out;

    const int N = in_sizes[2];      // 50000
    const int E = in_sizes[3];      // 800000
    const int* row = eidx;
    const int* col = eidx + E;

    // workspace layout
    char* p = (char*)d_ws;
    unsigned int* packed = (unsigned int*)p; p += (size_t)N * 4;
    float* dis      = (float*)p; p += (size_t)N * 4;
    float* sums     = (float*)p; p += (size_t)N_GRAPHS * 64 * 4;
    float* cntG     = (float*)p; p += (size_t)N_GRAPHS * 4;
    float* Wc       = (float*)p; p += (size_t)64 * N_CLASSES * 4;
    float* bc       = (float*)p; p += (size_t)N_CLASSES * 4;
    unsigned int* ell = (unsigned int*)p; p += (size_t)N * MAXDEG * 4;  // 12.8 MB
    float* bufF     = (float*)p; p += (size_t)N * 64 * 4;   // f32 h3 for pooling
    bf16*  xg       = (bf16*)p;  p += (size_t)N * 64 * 2;   // g0 = dis*x; reused as g2
    bf16*  gA       = (bf16*)p;  p += (size_t)N * 64 * 2;   // g1
    bf16*  gB       = xg;  // g2 aliases xg (g0 dead after layer 1)

    dim3 blk(256);
    int nodeG = (N + 255) / 256;           // 196
    int edgeG = (E + 255) / 256;           // 3125
    int bigG  = (N * 64 + 255) / 256;      // 12500

    init_k<<<nodeG, blk, 0, stream>>>(packed, sums, cntG, N);
    hist_k<<<edgeG, blk, 0, stream>>>(P, row, col, packed, ell, E);
    disxg_k<<<bigG, blk, 0, stream>>>(packed, x, dis, xg, ell, N);
    fold_k<<<(64 * N_CLASSES + 255) / 256, blk, 0, stream>>>(W3, b3, Wl, bl, Wc, bc);

    int aggG = (N + 3) / 4;  // 1 node per wave, 4 waves/block

    // Layer 1: g1 = dis*relu(agg(x) @ W1 + b1)
    agg_mm_k<1><<<aggG, blk, 0, stream>>>(xg, ell, packed, dis, W1, b1, nullptr, gA, N);
    // Layer 2: g2 = dis*relu(agg(h1) @ W2 + b2)
    agg_mm_k<1><<<aggG, blk, 0, stream>>>(gA, ell, packed, dis, W2, b2, nullptr, gB, N);
    // Layer 3 (pure agg; W3/b3 folded into classifier), f32 out for pooling
    agg_mm_k<0><<<aggG, blk, 0, stream>>>(gB, ell, packed, dis, nullptr, nullptr, bufF, nullptr, N);

    // pool + folded classifier
    int poolG = (N + 127) / 128;
    poolpart_k<<<poolG, blk, 0, stream>>>(bufF, batch, sums, cntG, N);
    classify_k<<<N_GRAPHS, dim3(64), 0, stream>>>(sums, cntG, Wc, bc, out);
}